// Round 6
// baseline (218.527 us; speedup 1.0000x reference)
//
#include <hip/hip_runtime.h>

typedef unsigned short u16;
typedef __bf16 bf16;
typedef __attribute__((ext_vector_type(8))) __bf16 bf16x8;  // MFMA A/B frag (4 VGPRs)
typedef __attribute__((ext_vector_type(4))) float f32x4;    // MFMA C/D frag

#define AS1(p) ((const __attribute__((address_space(1))) void*)(p))
#define AS3(p) ((__attribute__((address_space(3))) void*)(p))

__device__ __forceinline__ u16 f2bf(float f) {
  unsigned u = __builtin_bit_cast(unsigned, f);
  u += 0x7fffu + ((u >> 16) & 1u);
  return (u16)(u >> 16);
}

static constexpr int  B_ = 2, N_ = 2048, C_ = 1024, H_ = 8, DH_ = 128;
static constexpr long SZ_IN = (long)B_ * N_ * C_;  // 4,194,304 elems
static constexpr long SZ_W  = (long)C_ * C_;       // 1,048,576 elems

// ---------------------------------------------------------------------------
// Fused cast kernel: y=0/1 -> input fp32->bf16 cast; y=2 -> weight
// cast+transpose (x<1024: matrix z=x>>8, 64x64 tile = x&255). One launch
// instead of two (fewer launch gaps; paths are block-uniform).
// ---------------------------------------------------------------------------
__global__ void k_cast(const float* __restrict__ q, const float* __restrict__ kv,
                       const float* __restrict__ W0, const float* __restrict__ W1,
                       const float* __restrict__ W2, const float* __restrict__ W3,
                       u16* __restrict__ qb, u16* __restrict__ kvb,
                       u16* __restrict__ WT)
{
  __shared__ u16 t[64][65];
  int tid = threadIdx.x;
  if (blockIdx.y < 2) {
    const float* src = blockIdx.y ? kv : q;
    u16* dst = blockIdx.y ? kvb : qb;
    long i = ((long)blockIdx.x * 256 + tid) * 8;
    float4 a = *(const float4*)(src + i);
    float4 b = *(const float4*)(src + i + 4);
    uint4 v;
    v.x = f2bf(a.x) | ((unsigned)f2bf(a.y) << 16);
    v.y = f2bf(a.z) | ((unsigned)f2bf(a.w) << 16);
    v.z = f2bf(b.x) | ((unsigned)f2bf(b.y) << 16);
    v.w = f2bf(b.z) | ((unsigned)f2bf(b.w) << 16);
    *(uint4*)(dst + i) = v;
    return;
  }
  int x = blockIdx.x;
  if (x >= 1024) return;
  int z = x >> 8, tile = x & 255;
  const float* W = (z == 0) ? W0 : (z == 1) ? W1 : (z == 2) ? W2 : W3;
  u16* dst = WT + (long)z * SZ_W;
  int n0 = (tile & 15) * 64, k0 = (tile >> 4) * 64;
#pragma unroll
  for (int r = 0; r < 4; ++r) {
    int slot = r * 256 + tid;
    int row = slot >> 4, c4 = slot & 15;
    float4 a = *(const float4*)(W + (long)(k0 + row) * 1024 + n0 + c4 * 4);
    t[c4*4+0][row] = f2bf(a.x);
    t[c4*4+1][row] = f2bf(a.y);
    t[c4*4+2][row] = f2bf(a.z);
    t[c4*4+3][row] = f2bf(a.w);
  }
  __syncthreads();
#pragma unroll
  for (int r = 0; r < 4; ++r) {
    int slot = r * 256 + tid;
    int row = slot >> 4, c4 = slot & 15;
    uint2 v;
    v.x = t[row][c4*4+0] | ((unsigned)t[row][c4*4+1] << 16);
    v.y = t[row][c4*4+2] | ((unsigned)t[row][c4*4+3] << 16);
    *(uint2*)(dst + (long)(n0 + row) * 1024 + k0 + c4 * 4) = v;
  }
}

// ---------------------------------------------------------------------------
// m97-style GEMM mainloop with XOR bank swizzle (round-2-proven, unchanged).
// ---------------------------------------------------------------------------
__device__ __forceinline__ void gemm_main_128x128(
    const u16* __restrict__ A, const u16* __restrict__ BT,
    u16* lA, u16* lB, int m0, int n0, int tid, f32x4 acc[4][4])
{
  int w = tid >> 6, l = tid & 63, quad = l >> 4, lm = l & 15;
  int wm = w >> 1, wn = w & 1;
  int srow = tid >> 2, schunk = tid & 3;
  int sxw = (srow >> 1) & 3;
  int sxr = (lm >> 1) & 3;
  const u16* Ag = A + (long)(m0 + srow) * 1024 + (schunk ^ sxw) * 8;
  const u16* Bg = BT + (long)(n0 + srow) * 1024 + (schunk ^ sxw) * 8;
  u16* lAw = lA + w * 512;
  u16* lBw = lB + w * 512;
  for (int kb = 0; kb < 32; ++kb) {
    const u16* Agk = Ag + kb * 32;
    const u16* Bgk = Bg + kb * 32;
    __builtin_amdgcn_global_load_lds(AS1(Agk),           AS3(lAw),        16, 0, 0);
    __builtin_amdgcn_global_load_lds(AS1(Agk + 64*1024), AS3(lAw + 2048), 16, 0, 0);
    __builtin_amdgcn_global_load_lds(AS1(Bgk),           AS3(lBw),        16, 0, 0);
    __builtin_amdgcn_global_load_lds(AS1(Bgk + 64*1024), AS3(lBw + 2048), 16, 0, 0);
    __syncthreads();
    bf16x8 af[4], bfr[4];
#pragma unroll
    for (int mi = 0; mi < 4; ++mi)
      af[mi] = *(const bf16x8*)(lA + (wm*64 + mi*16 + lm)*32 + ((quad ^ sxr))*8);
#pragma unroll
    for (int ni = 0; ni < 4; ++ni)
      bfr[ni] = *(const bf16x8*)(lB + (wn*64 + ni*16 + lm)*32 + ((quad ^ sxr))*8);
#pragma unroll
    for (int mi = 0; mi < 4; ++mi)
#pragma unroll
      for (int ni = 0; ni < 4; ++ni)
        acc[mi][ni] = __builtin_amdgcn_mfma_f32_16x16x32_bf16(af[mi], bfr[ni], acc[mi][ni], 0, 0, 0);
    __syncthreads();
  }
}

// ---------------------------------------------------------------------------
// QKV projection v2 (unchanged, r6/r7-proven).
// ---------------------------------------------------------------------------
__global__ __launch_bounds__(256, 3)
void k_gemm_qkv(const u16* __restrict__ qb, const u16* __restrict__ kvb,
                const u16* __restrict__ wt,
                const float* __restrict__ bq, const float* __restrict__ bk,
                const float* __restrict__ bv,
                u16* __restrict__ Qb, u16* __restrict__ Kb, u16* __restrict__ VTb)
{
  __shared__ u16 lA[4096], lB[4096];
  int tid = threadIdx.x;
  int z = blockIdx.z;
  f32x4 acc[4][4] = {};
  int w = tid >> 6, l = tid & 63, quad = l >> 4, lm = l & 15;
  int wm = w >> 1, wn = w & 1;

  if (z == 2) {
    int m0 = blockIdx.y * 128, n0 = blockIdx.x * 128;
    gemm_main_128x128(kvb, wt + 2 * SZ_W, lA, lB, m0, n0, tid, acc);
#pragma unroll
    for (int ni = 0; ni < 4; ++ni) {
      int n = n0 + wn*64 + ni*16 + lm;       // channel
      float bb = bv[n];
      int h = n >> 7, dd = n & 127;
#pragma unroll
      for (int mi = 0; mi < 4; ++mi) {
        int mbase = m0 + wm*64 + mi*16 + quad*4;  // token (4 consecutive)
        int bidx = mbase >> 11, nn = mbase & 2047;
        u16 o0 = f2bf(acc[mi][ni][0] + bb), o1 = f2bf(acc[mi][ni][1] + bb);
        u16 o2 = f2bf(acc[mi][ni][2] + bb), o3 = f2bf(acc[mi][ni][3] + bb);
        uint2 v; v.x = o0 | ((unsigned)o1 << 16); v.y = o2 | ((unsigned)o3 << 16);
        *(uint2*)(VTb + ((long)(bidx*8 + h)*128 + dd)*2048 + nn) = v;
      }
    }
  } else {
    const u16* X = (z == 0) ? qb : kvb;
    const float* bias = (z == 0) ? bq : bk;
    u16* dst = (z == 0) ? Qb : Kb;
    float scale = (z == 0) ? 0.08838834764831845f : 1.0f;  // fold 1/sqrt(128)
    int m0 = blockIdx.x * 128, n0 = blockIdx.y * 128;
    gemm_main_128x128(wt + (long)z * SZ_W, X, lA, lB, m0, n0, tid, acc);
#pragma unroll
    for (int mi = 0; mi < 4; ++mi) {
      int chb = m0 + wm*64 + mi*16 + quad*4;   // channel base (4 consecutive)
      int h = chb >> 7, d = chb & 127;
      float4 bb = *(const float4*)(bias + chb);
#pragma unroll
      for (int ni = 0; ni < 4; ++ni) {
        int tok = n0 + wn*64 + ni*16 + lm;
        int bidx = tok >> 11, nn = tok & 2047;
        u16 o0 = f2bf((acc[mi][ni][0] + bb.x) * scale);
        u16 o1 = f2bf((acc[mi][ni][1] + bb.y) * scale);
        u16 o2 = f2bf((acc[mi][ni][2] + bb.z) * scale);
        u16 o3 = f2bf((acc[mi][ni][3] + bb.w) * scale);
        uint2 v; v.x = o0 | ((unsigned)o1 << 16); v.y = o2 | ((unsigned)o3 << 16);
        *(uint2*)(dst + ((long)(bidx*8 + h)*2048 + nn)*128 + d) = v;
      }
    }
  }
}

// ---------------------------------------------------------------------------
// Flash attention v14 — v13 template + 2 blocks/CU (barrier-domain overlap).
//
// Evidence chain: v11 (2333 cy/tile) == v12 (halved LDS reads+conflicts) ->
// not LDS-volume-bound. v13 (KVBLK=64) only -7% though per-tile count
// halved -> "fixed cost" scales with tile. Remaining signature: MfmaUtil 23,
// VALU 28, ~50% both-pipes-idle, grid 256 = 1 block/CU: every barrier
// drains the WHOLE CU (vmcnt0+lgkmcnt0 before s_barrier) and the lockstep
// re-ramp (8 waves flood kf reads, then all hit exp together) has no other
// resident block to fill it (m114/m103: barrier stall needs co-residency).
//
// v14 = v13 with QBLK 128->64: 4 waves x 16 q-rows (256 thr), grid (16,32)
// = 512 blocks = 2 blocks/CU (LDS 72KB, 2x72 <= 160KB). Two independent
// barrier domains per CU: while one drains/ramps, the other computes.
// Cost: K/V staged per 64-row q-block -> 2x TA traffic (~18.5 B/cyc/CU,
// under the 24.6 ceiling; L2-resident, FETCH flat). All swizzles, staging
// formulas and read formulas are v13-identical; stage loop j<2 -> j<4.
// LDS u16: bufK 2x8192 [0,16384) | bufV 2x8192 [16384,32768) | lP 4x1024
// [32768,36864) = 72 KB.
// ---------------------------------------------------------------------------
__global__ __launch_bounds__(256, 2)
void k_attn(const u16* __restrict__ Qb, const u16* __restrict__ Kb,
            const u16* __restrict__ VTb, u16* __restrict__ Sout)
{
  __shared__ u16 smem[36864];   // 72 KB
  u16* lP = smem + 32768;

  int tid = threadIdx.x;
  int w = tid >> 6, l = tid & 63, quad = l >> 4, lm = l & 15;
  int bh = blockIdx.x;             // XCD = (x + 16y) % 8 = bh % 8 -> 2 bh/XCD
  int q0 = blockIdx.y * 64 + w * 16;
  const u16* Qg = Qb + ((long)bh * 2048 + q0) * 128;
  const u16* Kg = Kb + (long)bh * 2048 * 128;
  const u16* Vg = VTb + (long)bh * 128 * 2048;
  u16* lPw = lP + w * 1024;

  // register-resident Q (16 q-rows, DH=128), scale pre-folded at projection
  bf16x8 qf[4];
#pragma unroll
  for (int kk = 0; kk < 4; ++kk)
    qf[kk] = *(const bf16x8*)(Qg + (long)lm * 128 + kk*32 + quad*8);

  f32x4 accO[8] = {};
  float sumP[4] = {};

  // Cooperative staging of a 64-key tile: K 64x128 (1024 16B chunks) and
  // V 128x64 (1024 chunks); 256 lanes x 4 DMA each for K and for V.
  // K: chunk stored at c^(r&7) within row (v8/v11-proven).
  // V: per d-row 8 chunks, stored slot = c^(d&7); DMA dest lane-linear,
  // swizzle applied to the global source address (m173 pattern).
  auto stage = [&](int tt) {
    int buf = (tt & 1) * 8192;
#pragma unroll
    for (int j = 0; j < 4; ++j) {
      int s = j*256 + tid;             // 0..1023
      int r = s >> 4, c = s & 15;      // key row 0..63, chunk 0..15
      __builtin_amdgcn_global_load_lds(
          AS1(Kg + (long)(tt*64 + r)*128 + ((c ^ (r & 7)) * 8)),
          AS3(smem + buf + (j*256 + w*64)*8), 16, 0, 0);
    }
#pragma unroll
    for (int j = 0; j < 4; ++j) {
      int s = j*256 + tid;             // 0..1023
      int d = s >> 3, slot = s & 7;    // d row 0..127, stored slot
      int c = slot ^ (d & 7);          // logical chunk (8 per 64-key row)
      __builtin_amdgcn_global_load_lds(
          AS1(Vg + (long)d*2048 + tt*64 + c*8),
          AS3(smem + 16384 + buf + (j*256 + w*64)*8), 16, 0, 0);
    }
  };

  stage(0);

#pragma unroll 1
  for (int t = 0; t < 32; ++t) {
    __syncthreads();          // drains stage(t) DMA; WAR-protects buf (t+1)&1
    if (t < 31) stage(t + 1);

    const u16* bK = smem + (t & 1) * 8192;
    const u16* bV = smem + 16384 + (t & 1) * 8192;

    // QK^T: 16q x 64k from shared LDS K tile
    f32x4 accS[4] = {};
#pragma unroll
    for (int kk = 0; kk < 4; ++kk)
#pragma unroll
      for (int ni = 0; ni < 4; ++ni) {
        bf16x8 kf = *(const bf16x8*)(bK + (ni*16 + lm)*128 + (((kk*4 + quad) ^ (lm & 7)))*8);
        accS[ni] = __builtin_amdgcn_mfma_f32_16x16x32_bf16(qf[kk], kf, accS[ni], 0, 0, 0);
      }

    // V B-frags for key-half 0 issued early (independent of softmax)
    bf16x8 vfk[8];
#pragma unroll
    for (int ni = 0; ni < 8; ++ni)
      vfk[ni] = *(const bf16x8*)(bV + ((ni*16 + lm)*8 + ((0*4 + quad) ^ (lm & 7)))*8);

    // no-max softmax: p = exp(s); per-lane partial sums; P -> swizzled LDS
    // (two 32-key halves, v11 formulas per half)
#pragma unroll
    for (int r = 0; r < 4; ++r) {
      int R = quad*4 + r;
      int xr = (quad*2 + (r >> 1)) & 3;
#pragma unroll
      for (int ni = 0; ni < 4; ++ni) {
        float p = __expf(accS[ni][r]);
        sumP[r] += p;
        int kh = ni >> 1;
        int ch = (ni & 1)*2 + (lm >> 3);
        lPw[kh*512 + (R*4 + (ch ^ xr))*8 + (lm & 7)] = f2bf(p);
      }
    }

    // key-half 0: P A-frag + PV
    bf16x8 pf = *(const bf16x8*)(lPw + (lm*4 + (quad ^ ((lm >> 1) & 3)))*8);
#pragma unroll
    for (int ni = 0; ni < 8; ++ni)
      accO[ni] = __builtin_amdgcn_mfma_f32_16x16x32_bf16(pf, vfk[ni], accO[ni], 0, 0, 0);

    // key-half 1: V frags, P A-frag, PV
#pragma unroll
    for (int ni = 0; ni < 8; ++ni)
      vfk[ni] = *(const bf16x8*)(bV + ((ni*16 + lm)*8 + ((1*4 + quad) ^ (lm & 7)))*8);
    pf = *(const bf16x8*)(lPw + 512 + (lm*4 + (quad ^ ((lm >> 1) & 3)))*8);
#pragma unroll
    for (int ni = 0; ni < 8; ++ni)
      accO[ni] = __builtin_amdgcn_mfma_f32_16x16x32_bf16(pf, vfk[ni], accO[ni], 0, 0, 0);
  }

  // ---- row-sum reduce (16 col-lanes per row) + normalize + store ----
  // Each wave owns its 16 rows completely: no cross-wave merge needed.
  int b = bh >> 3, h = bh & 7;
#pragma unroll
  for (int r = 0; r < 4; ++r) {
    float s = sumP[r];
    s += __shfl_xor(s, 1);
    s += __shfl_xor(s, 2);
    s += __shfl_xor(s, 4);
    s += __shfl_xor(s, 8);
    float linv = 1.f / s;
#pragma unroll
    for (int ni = 0; ni < 8; ++ni) {
      float v = accO[ni][r] * linv;
      Sout[((long)(b*2048 + q0 + quad*4 + r))*1024 + h*128 + ni*16 + lm] = f2bf(v);
    }
  }
}

// ---------------------------------------------------------------------------
// Output projection v2 (unchanged, r6/r7-proven).
// ---------------------------------------------------------------------------
__global__ __launch_bounds__(256, 3)
void k_gemm_out(const u16* __restrict__ S, const u16* __restrict__ WoT,
                const float* __restrict__ bo, float* __restrict__ out)
{
  __shared__ u16 lA[4096], lB[4096];
  int tid = threadIdx.x;
  int m0 = blockIdx.x * 128, n0 = blockIdx.y * 128;   // m = channel, n = token
  f32x4 acc[4][4] = {};
  gemm_main_128x128(WoT, S, lA, lB, m0, n0, tid, acc);

  int w = tid >> 6, l = tid & 63, quad = l >> 4, lm = l & 15;
  int wm = w >> 1, wn = w & 1;
#pragma unroll
  for (int mi = 0; mi < 4; ++mi) {
    int chb = m0 + wm*64 + mi*16 + quad*4;   // 4 consecutive channels
    float4 bb = *(const float4*)(bo + chb);
#pragma unroll
    for (int ni = 0; ni < 4; ++ni) {
      int tok = n0 + wn*64 + ni*16 + lm;
      float4 v;
      v.x = acc[mi][ni][0] + bb.x;
      v.y = acc[mi][ni][1] + bb.y;
      v.z = acc[mi][ni][2] + bb.z;
      v.w = acc[mi][ni][3] + bb.w;
      *(float4*)(out + (long)tok * 1024 + chb) = v;
    }
  }
}

// ---------------------------------------------------------------------------
// ws layout (u16 elems), 48 MiB: ABUF (q_bf16, reused for summed), KVB,
// WT 4x, Qb/Kb [b][h][n][d], VTb [b][h][d][n]
// ---------------------------------------------------------------------------
extern "C" void kernel_launch(void* const* d_in, const int* in_sizes, int n_in,
                              void* d_out, int out_size, void* d_ws, size_t ws_size,
                              hipStream_t stream)
{
  const float* inq  = (const float*)d_in[0];
  const float* inkv = (const float*)d_in[1];
  const float* Wq = (const float*)d_in[2];
  const float* bq = (const float*)d_in[3];
  const float* Wk = (const float*)d_in[4];
  const float* bk = (const float*)d_in[5];
  const float* Wv = (const float*)d_in[6];
  const float* bv = (const float*)d_in[7];
  const float* Wo = (const float*)d_in[8];
  const float* bo = (const float*)d_in[9];

  u16* ws   = (u16*)d_ws;
  u16* ABUF = ws;
  u16* KVB  = ws + SZ_IN;
  u16* WT   = ws + 2 * SZ_IN;
  u16* Qb   = WT + 4 * SZ_W;
  u16* Kb   = Qb + SZ_IN;
  u16* VTb  = Kb + SZ_IN;

  k_cast    <<<dim3(2048, 3),   256, 0, stream>>>(inq, inkv, Wq, Wk, Wv, Wo, ABUF, KVB, WT);
  k_gemm_qkv<<<dim3(8, 32, 3),  256, 0, stream>>>(ABUF, KVB, WT, bq, bk, bv, Qb, Kb, VTb);
  k_attn    <<<dim3(16, 32),    256, 0, stream>>>(Qb, Kb, VTb, ABUF);
  k_gemm_out<<<dim3(8, 32),     256, 0, stream>>>(ABUF, WT + 3 * SZ_W, bo, (float*)d_out);
}

// Round 7
// 214.865 us; speedup vs baseline: 1.0170x; 1.0170x over previous
//
#include <hip/hip_runtime.h>

typedef unsigned short u16;
typedef __bf16 bf16;
typedef __attribute__((ext_vector_type(8))) __bf16 bf16x8;   // MFMA A/B frag (4 VGPRs)
typedef __attribute__((ext_vector_type(4))) float f32x4;     // 16x16 MFMA C/D frag
typedef __attribute__((ext_vector_type(16))) float f32x16;   // 32x32 MFMA C/D frag

#define AS1(p) ((const __attribute__((address_space(1))) void*)(p))
#define AS3(p) ((__attribute__((address_space(3))) void*)(p))

__device__ __forceinline__ u16 f2bf(float f) {
  unsigned u = __builtin_bit_cast(unsigned, f);
  u += 0x7fffu + ((u >> 16) & 1u);
  return (u16)(u >> 16);
}

static constexpr int  B_ = 2, N_ = 2048, C_ = 1024, H_ = 8, DH_ = 128;
static constexpr long SZ_IN = (long)B_ * N_ * C_;  // 4,194,304 elems
static constexpr long SZ_W  = (long)C_ * C_;       // 1,048,576 elems

// ---------------------------------------------------------------------------
// Fused cast kernel (unchanged).
// ---------------------------------------------------------------------------
__global__ void k_cast(const float* __restrict__ q, const float* __restrict__ kv,
                       const float* __restrict__ W0, const float* __restrict__ W1,
                       const float* __restrict__ W2, const float* __restrict__ W3,
                       u16* __restrict__ qb, u16* __restrict__ kvb,
                       u16* __restrict__ WT)
{
  __shared__ u16 t[64][65];
  int tid = threadIdx.x;
  if (blockIdx.y < 2) {
    const float* src = blockIdx.y ? kv : q;
    u16* dst = blockIdx.y ? kvb : qb;
    long i = ((long)blockIdx.x * 256 + tid) * 8;
    float4 a = *(const float4*)(src + i);
    float4 b = *(const float4*)(src + i + 4);
    uint4 v;
    v.x = f2bf(a.x) | ((unsigned)f2bf(a.y) << 16);
    v.y = f2bf(a.z) | ((unsigned)f2bf(a.w) << 16);
    v.z = f2bf(b.x) | ((unsigned)f2bf(b.y) << 16);
    v.w = f2bf(b.z) | ((unsigned)f2bf(b.w) << 16);
    *(uint4*)(dst + i) = v;
    return;
  }
  int x = blockIdx.x;
  if (x >= 1024) return;
  int z = x >> 8, tile = x & 255;
  const float* W = (z == 0) ? W0 : (z == 1) ? W1 : (z == 2) ? W2 : W3;
  u16* dst = WT + (long)z * SZ_W;
  int n0 = (tile & 15) * 64, k0 = (tile >> 4) * 64;
#pragma unroll
  for (int r = 0; r < 4; ++r) {
    int slot = r * 256 + tid;
    int row = slot >> 4, c4 = slot & 15;
    float4 a = *(const float4*)(W + (long)(k0 + row) * 1024 + n0 + c4 * 4);
    t[c4*4+0][row] = f2bf(a.x);
    t[c4*4+1][row] = f2bf(a.y);
    t[c4*4+2][row] = f2bf(a.z);
    t[c4*4+3][row] = f2bf(a.w);
  }
  __syncthreads();
#pragma unroll
  for (int r = 0; r < 4; ++r) {
    int slot = r * 256 + tid;
    int row = slot >> 4, c4 = slot & 15;
    uint2 v;
    v.x = t[row][c4*4+0] | ((unsigned)t[row][c4*4+1] << 16);
    v.y = t[row][c4*4+2] | ((unsigned)t[row][c4*4+3] << 16);
    *(uint2*)(dst + (long)(n0 + row) * 1024 + k0 + c4 * 4) = v;
  }
}

// ---------------------------------------------------------------------------
// m97-style GEMM mainloop (unchanged).
// ---------------------------------------------------------------------------
__device__ __forceinline__ void gemm_main_128x128(
    const u16* __restrict__ A, const u16* __restrict__ BT,
    u16* lA, u16* lB, int m0, int n0, int tid, f32x4 acc[4][4])
{
  int w = tid >> 6, l = tid & 63, quad = l >> 4, lm = l & 15;
  int wm = w >> 1, wn = w & 1;
  int srow = tid >> 2, schunk = tid & 3;
  int sxw = (srow >> 1) & 3;
  int sxr = (lm >> 1) & 3;
  const u16* Ag = A + (long)(m0 + srow) * 1024 + (schunk ^ sxw) * 8;
  const u16* Bg = BT + (long)(n0 + srow) * 1024 + (schunk ^ sxw) * 8;
  u16* lAw = lA + w * 512;
  u16* lBw = lB + w * 512;
  for (int kb = 0; kb < 32; ++kb) {
    const u16* Agk = Ag + kb * 32;
    const u16* Bgk = Bg + kb * 32;
    __builtin_amdgcn_global_load_lds(AS1(Agk),           AS3(lAw),        16, 0, 0);
    __builtin_amdgcn_global_load_lds(AS1(Agk + 64*1024), AS3(lAw + 2048), 16, 0, 0);
    __builtin_amdgcn_global_load_lds(AS1(Bgk),           AS3(lBw),        16, 0, 0);
    __builtin_amdgcn_global_load_lds(AS1(Bgk + 64*1024), AS3(lBw + 2048), 16, 0, 0);
    __syncthreads();
    bf16x8 af[4], bfr[4];
#pragma unroll
    for (int mi = 0; mi < 4; ++mi)
      af[mi] = *(const bf16x8*)(lA + (wm*64 + mi*16 + lm)*32 + ((quad ^ sxr))*8);
#pragma unroll
    for (int ni = 0; ni < 4; ++ni)
      bfr[ni] = *(const bf16x8*)(lB + (wn*64 + ni*16 + lm)*32 + ((quad ^ sxr))*8);
#pragma unroll
    for (int mi = 0; mi < 4; ++mi)
#pragma unroll
      for (int ni = 0; ni < 4; ++ni)
        acc[mi][ni] = __builtin_amdgcn_mfma_f32_16x16x32_bf16(af[mi], bfr[ni], acc[mi][ni], 0, 0, 0);
    __syncthreads();
  }
}

// ---------------------------------------------------------------------------
// QKV projection v2 (unchanged).
// ---------------------------------------------------------------------------
__global__ __launch_bounds__(256, 3)
void k_gemm_qkv(const u16* __restrict__ qb, const u16* __restrict__ kvb,
                const u16* __restrict__ wt,
                const float* __restrict__ bq, const float* __restrict__ bk,
                const float* __restrict__ bv,
                u16* __restrict__ Qb, u16* __restrict__ Kb, u16* __restrict__ VTb)
{
  __shared__ u16 lA[4096], lB[4096];
  int tid = threadIdx.x;
  int z = blockIdx.z;
  f32x4 acc[4][4] = {};
  int w = tid >> 6, l = tid & 63, quad = l >> 4, lm = l & 15;
  int wm = w >> 1, wn = w & 1;

  if (z == 2) {
    int m0 = blockIdx.y * 128, n0 = blockIdx.x * 128;
    gemm_main_128x128(kvb, wt + 2 * SZ_W, lA, lB, m0, n0, tid, acc);
#pragma unroll
    for (int ni = 0; ni < 4; ++ni) {
      int n = n0 + wn*64 + ni*16 + lm;       // channel
      float bb = bv[n];
      int h = n >> 7, dd = n & 127;
#pragma unroll
      for (int mi = 0; mi < 4; ++mi) {
        int mbase = m0 + wm*64 + mi*16 + quad*4;  // token (4 consecutive)
        int bidx = mbase >> 11, nn = mbase & 2047;
        u16 o0 = f2bf(acc[mi][ni][0] + bb), o1 = f2bf(acc[mi][ni][1] + bb);
        u16 o2 = f2bf(acc[mi][ni][2] + bb), o3 = f2bf(acc[mi][ni][3] + bb);
        uint2 v; v.x = o0 | ((unsigned)o1 << 16); v.y = o2 | ((unsigned)o3 << 16);
        *(uint2*)(VTb + ((long)(bidx*8 + h)*128 + dd)*2048 + nn) = v;
      }
    }
  } else {
    const u16* X = (z == 0) ? qb : kvb;
    const float* bias = (z == 0) ? bq : bk;
    u16* dst = (z == 0) ? Qb : Kb;
    float scale = (z == 0) ? 0.08838834764831845f : 1.0f;  // fold 1/sqrt(128)
    int m0 = blockIdx.x * 128, n0 = blockIdx.y * 128;
    gemm_main_128x128(wt + (long)z * SZ_W, X, lA, lB, m0, n0, tid, acc);
#pragma unroll
    for (int mi = 0; mi < 4; ++mi) {
      int chb = m0 + wm*64 + mi*16 + quad*4;   // channel base (4 consecutive)
      int h = chb >> 7, d = chb & 127;
      float4 bb = *(const float4*)(bias + chb);
#pragma unroll
      for (int ni = 0; ni < 4; ++ni) {
        int tok = n0 + wn*64 + ni*16 + lm;
        int bidx = tok >> 11, nn = tok & 2047;
        u16 o0 = f2bf((acc[mi][ni][0] + bb.x) * scale);
        u16 o1 = f2bf((acc[mi][ni][1] + bb.y) * scale);
        u16 o2 = f2bf((acc[mi][ni][2] + bb.z) * scale);
        u16 o3 = f2bf((acc[mi][ni][3] + bb.w) * scale);
        uint2 v; v.x = o0 | ((unsigned)o1 << 16); v.y = o2 | ((unsigned)o3 << 16);
        *(uint2*)(dst + ((long)(bidx*8 + h)*2048 + nn)*128 + d) = v;
      }
    }
  }
}

// ---------------------------------------------------------------------------
// Flash attention v15 — 32x32 MFMA + paired-wave key-split (LDS bytes/FLOP).
//
// LDS accounting across v8-v14: v13 (best, 57.8us) moves 320KB LDS per
// CU-tile (kf 128 + vf 128 + pf 16 + DMA 32 + Pw 16) ~ 3765cy at 85 B/cy
// (m134) + 512 conflict-cy = 4280 of 4334 observed cy/tile: LDS-pipe
// SATURATED. v12 (92KB, 37 B/cy) wasn't LDS-bound but ran at 1 wave/SIMD
// where pipes serialize -> equal time. Redundancy is structural: each of 8
// waves reads the whole K/V tile; 16x16x32 MFMA does 8192 MACs per KB of
// B-operand.
//
// v15: 32x32x16 MFMA = 16384 MACs/KB of B. 32 q-rows can't be per-wave at
// full occupancy (32768 q-rows = 256CU x 8w x 16 exactly), so waves PAIR on
// 32 shared q-rows and split the 64-key tile: wave (qg,kh), qg in [0,4),
// kh = key half. Per wave/tile: 8 kf + 8 vf + 2 pf = 18KB LDS reads (vs 34).
// CU-tile ~192KB -> ~2400-2900cy vs MFMA floor 1242cy.
// Layouts (from HW-verified 32x32 C/D: col=lane&31, row=(reg&3)+8*(reg>>2)
// +4*(lane>>5)): A/B frags lane l: row/col=l&31, k=(l>>5)*8+j.
// K LDS: [64 rows][16 chunks], chunk stored at c^(r&15) (2-way reads).
// V LDS: [128 d][8 chunks], chunk stored at c^(d&7) (4-way reads, accepted).
// P: per-wave [32 q][40 u16] pad -> 16B-aligned b128 reads.
// O-merge: kh=1 parks 32q x 128d f32 in lO (64KB, overlays bufK/V), kh=0
// combines + normalizes (v8-proven pattern). Row sums via lStat.
// LDS u16: bufK 2x8192 [0,16384) | bufV 2x8192 [16384,32768) | lP 8x1280
// [32768,43008) | lStat 512 [43008,43520) = 85 KB -> 1 block/CU, 8 waves.
// ---------------------------------------------------------------------------
__global__ __launch_bounds__(512, 2)
void k_attn(const u16* __restrict__ Qb, const u16* __restrict__ Kb,
            const u16* __restrict__ VTb, u16* __restrict__ Sout)
{
  __shared__ u16 smem[43520];   // 85 KB
  u16*   lP    = smem + 32768;
  float* lStat = (float*)(smem + 43008);  // [4 qg][2 kh][32 q]

  int tid = threadIdx.x;
  int w = tid >> 6, l = tid & 63;
  int l5 = l >> 5, c31 = l & 31;
  int qg = w >> 1, kh = w & 1;
  int bh = blockIdx.x;             // XCD = bh % 8 -> 2 bh per XCD L2
  int q0 = blockIdx.y * 128 + qg * 32;
  const u16* Qg = Qb + ((long)bh * 2048 + q0) * 128;
  const u16* Kg = Kb + (long)bh * 2048 * 128;
  const u16* Vg = VTb + (long)bh * 128 * 2048;
  u16* lPw = lP + w * 1280;        // [32 q][40]

  // register-resident Q: qf[c] = Q[q=c31][d = c*16 + l5*8 + j]
  bf16x8 qf[8];
#pragma unroll
  for (int c = 0; c < 8; ++c)
    qf[c] = *(const bf16x8*)(Qg + (long)c31 * 128 + c*16 + l5*8);

  f32x16 accO[4] = {};   // [dtile]; row=q via R(g,l5), col=d=dtile*32+c31
  float sumP[16] = {};   // per-reg row partial sums

  // Cooperative staging of a 64-key tile (1024 x 16B chunks each for K,V);
  // 512 lanes x 2 DMA each. Dest lane-linear; swizzle on global src (m173).
  auto stage = [&](int tt) {
    int bufK = (tt & 1) * 8192;
    int bufV = 16384 + (tt & 1) * 8192;
#pragma unroll
    for (int j = 0; j < 2; ++j) {
      int s = j*512 + tid;             // 0..1023
      int r = s >> 4, sl = s & 15;     // key row 0..63, stored slot
      __builtin_amdgcn_global_load_lds(
          AS1(Kg + (long)(tt*64 + r)*128 + ((sl ^ (r & 15)) * 8)),
          AS3(smem + bufK + (j*512 + w*64)*8), 16, 0, 0);
    }
#pragma unroll
    for (int j = 0; j < 2; ++j) {
      int s = j*512 + tid;             // 0..1023
      int d = s >> 3, sl = s & 7;      // d row 0..127, stored slot
      __builtin_amdgcn_global_load_lds(
          AS1(Vg + (long)d*2048 + tt*64 + ((sl ^ (d & 7)) * 8)),
          AS3(smem + bufV + (j*512 + w*64)*8), 16, 0, 0);
    }
  };

  stage(0);

#pragma unroll 1
  for (int t = 0; t < 32; ++t) {
    __syncthreads();          // drains stage(t) DMA; WAR-protects buf (t+1)&1
    if (t < 31) stage(t + 1);

    const u16* bK = smem + (t & 1) * 8192;
    const u16* bV = smem + 16384 + (t & 1) * 8192;

    // QK^T: 32q x 32k (wave's key half), K-contraction 128d = 8 MFMAs.
    // Two accumulators break the in-tile dependency chain.
    f32x16 accS[2] = {};
#pragma unroll
    for (int c = 0; c < 8; ++c) {
      int r = kh*32 + c31;                       // key row in 64-tile
      bf16x8 kf = *(const bf16x8*)(bK + (r*16 + ((2*c + l5) ^ (l & 15)))*8);
      accS[c & 1] = __builtin_amdgcn_mfma_f32_32x32x16_bf16(qf[c], kf, accS[c & 1], 0, 0, 0);
    }

    // no-max softmax: p = exp(s); per-lane partials; P -> padded LDS rows
#pragma unroll
    for (int g = 0; g < 16; ++g) {
      int R = (g & 3) + 8*(g >> 2) + 4*l5;       // q row (HW D-layout)
      float p = __expf(accS[0][g] + accS[1][g]);
      sumP[g] += p;
      lPw[R*40 + c31] = f2bf(p);                 // col = key = c31
    }

    // PV: O[32q][128d] += P[32q][32k] V[32k][128d], 2 k-steps x 4 d-tiles
#pragma unroll
    for (int ks = 0; ks < 2; ++ks) {
      bf16x8 pf = *(const bf16x8*)(lPw + c31*40 + ks*16 + l5*8);
#pragma unroll
      for (int dt = 0; dt < 4; ++dt) {
        int d = dt*32 + c31;
        int cc = kh*4 + ks*2 + l5;               // logical key-chunk in d-row
        bf16x8 vf = *(const bf16x8*)(bV + (d*8 + (cc ^ (d & 7)))*8);
        accO[dt] = __builtin_amdgcn_mfma_f32_32x32x16_bf16(pf, vf, accO[dt], 0, 0, 0);
      }
    }
  }

  // ---- row-sum reduce across the 32 key-lanes + publish per-half sums ----
#pragma unroll
  for (int g = 0; g < 16; ++g) {
    float s = sumP[g];
    s += __shfl_xor(s, 1);
    s += __shfl_xor(s, 2);
    s += __shfl_xor(s, 4);
    s += __shfl_xor(s, 8);
    s += __shfl_xor(s, 16);
    sumP[g] = s;
    int R = (g & 3) + 8*(g >> 2) + 4*l5;
    lStat[(qg*2 + kh)*32 + R] = s;      // 32 lanes same val: benign
  }

  // ---- pair merge: kh=1 parks unnormalized O, kh=0 combines ----
  float* lO = (float*)smem;   // [4 qg][32 q][128 d] f32 = 64 KB over bufK/V
  __syncthreads();            // all tile reads done; lStat visible
  if (kh == 1) {
#pragma unroll
    for (int dt = 0; dt < 4; ++dt)
#pragma unroll
      for (int g = 0; g < 16; ++g) {
        int R = (g & 3) + 8*(g >> 2) + 4*l5;
        lO[(qg*32 + R)*128 + dt*32 + c31] = accO[dt][g];
      }
  }
  __syncthreads();
  if (kh == 0) {
    int b = bh >> 3, h = bh & 7;
#pragma unroll
    for (int g = 0; g < 16; ++g) {
      int R = (g & 3) + 8*(g >> 2) + 4*l5;
      float linv = 1.f / (lStat[(qg*2)*32 + R] + lStat[(qg*2 + 1)*32 + R]);
#pragma unroll
      for (int dt = 0; dt < 4; ++dt) {
        float v = (accO[dt][g] + lO[(qg*32 + R)*128 + dt*32 + c31]) * linv;
        Sout[((long)(b*2048 + q0 + R))*1024 + h*128 + dt*32 + c31] = f2bf(v);
      }
    }
  }
}

// ---------------------------------------------------------------------------
// Output projection v2 (unchanged).
// ---------------------------------------------------------------------------
__global__ __launch_bounds__(256, 3)
void k_gemm_out(const u16* __restrict__ S, const u16* __restrict__ WoT,
                const float* __restrict__ bo, float* __restrict__ out)
{
  __shared__ u16 lA[4096], lB[4096];
  int tid = threadIdx.x;
  int m0 = blockIdx.x * 128, n0 = blockIdx.y * 128;   // m = channel, n = token
  f32x4 acc[4][4] = {};
  gemm_main_128x128(WoT, S, lA, lB, m0, n0, tid, acc);

  int w = tid >> 6, l = tid & 63, quad = l >> 4, lm = l & 15;
  int wm = w >> 1, wn = w & 1;
#pragma unroll
  for (int mi = 0; mi < 4; ++mi) {
    int chb = m0 + wm*64 + mi*16 + quad*4;   // 4 consecutive channels
    float4 bb = *(const float4*)(bo + chb);
#pragma unroll
    for (int ni = 0; ni < 4; ++ni) {
      int tok = n0 + wn*64 + ni*16 + lm;
      float4 v;
      v.x = acc[mi][ni][0] + bb.x;
      v.y = acc[mi][ni][1] + bb.y;
      v.z = acc[mi][ni][2] + bb.z;
      v.w = acc[mi][ni][3] + bb.w;
      *(float4*)(out + (long)tok * 1024 + chb) = v;
    }
  }
}

// ---------------------------------------------------------------------------
// ws layout (u16 elems), 48 MiB: ABUF (q_bf16, reused for summed), KVB,
// WT 4x, Qb/Kb [b][h][n][d], VTb [b][h][d][n]
// ---------------------------------------------------------------------------
extern "C" void kernel_launch(void* const* d_in, const int* in_sizes, int n_in,
                              void* d_out, int out_size, void* d_ws, size_t ws_size,
                              hipStream_t stream)
{
  const float* inq  = (const float*)d_in[0];
  const float* inkv = (const float*)d_in[1];
  const float* Wq = (const float*)d_in[2];
  const float* bq = (const float*)d_in[3];
  const float* Wk = (const float*)d_in[4];
  const float* bk = (const float*)d_in[5];
  const float* Wv = (const float*)d_in[6];
  const float* bv = (const float*)d_in[7];
  const float* Wo = (const float*)d_in[8];
  const float* bo = (const float*)d_in[9];

  u16* ws   = (u16*)d_ws;
  u16* ABUF = ws;
  u16* KVB  = ws + SZ_IN;
  u16* WT   = ws + 2 * SZ_IN;
  u16* Qb   = WT + 4 * SZ_W;
  u16* Kb   = Qb + SZ_IN;
  u16* VTb  = Kb + SZ_IN;

  k_cast    <<<dim3(2048, 3),   256, 0, stream>>>(inq, inkv, Wq, Wk, Wv, Wo, ABUF, KVB, WT);
  k_gemm_qkv<<<dim3(8, 32, 3),  256, 0, stream>>>(ABUF, KVB, WT, bq, bk, bv, Qb, Kb, VTb);
  k_attn    <<<dim3(16, 16),    512, 0, stream>>>(Qb, Kb, VTb, ABUF);
  k_gemm_out<<<dim3(8, 32),     256, 0, stream>>>(ABUF, WT + 3 * SZ_W, bo, (float*)d_out);
}

// Round 8
// 212.465 us; speedup vs baseline: 1.0285x; 1.0113x over previous
//
#include <hip/hip_runtime.h>

typedef unsigned short u16;
typedef __bf16 bf16;
typedef __attribute__((ext_vector_type(8))) __bf16 bf16x8;   // MFMA A/B frag (4 VGPRs)
typedef __attribute__((ext_vector_type(4))) float f32x4;     // 16x16 MFMA C/D frag
typedef __attribute__((ext_vector_type(16))) float f32x16;   // 32x32 MFMA C/D frag

#define AS1(p) ((const __attribute__((address_space(1))) void*)(p))
#define AS3(p) ((__attribute__((address_space(3))) void*)(p))

__device__ __forceinline__ u16 f2bf(float f) {
  unsigned u = __builtin_bit_cast(unsigned, f);
  u += 0x7fffu + ((u >> 16) & 1u);
  return (u16)(u >> 16);
}

// packed bf16 pair (RNE via compiler bf16 casts; may fuse to v_cvt_pk_bf16_f32)
__device__ __forceinline__ unsigned pkbf(float a, float b) {
  unsigned lo = (unsigned)__builtin_bit_cast(unsigned short, (__bf16)a);
  unsigned hi = (unsigned)__builtin_bit_cast(unsigned short, (__bf16)b);
  return lo | (hi << 16);
}

static constexpr int  B_ = 2, N_ = 2048, C_ = 1024, H_ = 8, DH_ = 128;
static constexpr long SZ_IN = (long)B_ * N_ * C_;  // 4,194,304 elems
static constexpr long SZ_W  = (long)C_ * C_;       // 1,048,576 elems

// ---------------------------------------------------------------------------
// Fused cast kernel (unchanged).
// ---------------------------------------------------------------------------
__global__ void k_cast(const float* __restrict__ q, const float* __restrict__ kv,
                       const float* __restrict__ W0, const float* __restrict__ W1,
                       const float* __restrict__ W2, const float* __restrict__ W3,
                       u16* __restrict__ qb, u16* __restrict__ kvb,
                       u16* __restrict__ WT)
{
  __shared__ u16 t[64][65];
  int tid = threadIdx.x;
  if (blockIdx.y < 2) {
    const float* src = blockIdx.y ? kv : q;
    u16* dst = blockIdx.y ? kvb : qb;
    long i = ((long)blockIdx.x * 256 + tid) * 8;
    float4 a = *(const float4*)(src + i);
    float4 b = *(const float4*)(src + i + 4);
    uint4 v;
    v.x = f2bf(a.x) | ((unsigned)f2bf(a.y) << 16);
    v.y = f2bf(a.z) | ((unsigned)f2bf(a.w) << 16);
    v.z = f2bf(b.x) | ((unsigned)f2bf(b.y) << 16);
    v.w = f2bf(b.z) | ((unsigned)f2bf(b.w) << 16);
    *(uint4*)(dst + i) = v;
    return;
  }
  int x = blockIdx.x;
  if (x >= 1024) return;
  int z = x >> 8, tile = x & 255;
  const float* W = (z == 0) ? W0 : (z == 1) ? W1 : (z == 2) ? W2 : W3;
  u16* dst = WT + (long)z * SZ_W;
  int n0 = (tile & 15) * 64, k0 = (tile >> 4) * 64;
#pragma unroll
  for (int r = 0; r < 4; ++r) {
    int slot = r * 256 + tid;
    int row = slot >> 4, c4 = slot & 15;
    float4 a = *(const float4*)(W + (long)(k0 + row) * 1024 + n0 + c4 * 4);
    t[c4*4+0][row] = f2bf(a.x);
    t[c4*4+1][row] = f2bf(a.y);
    t[c4*4+2][row] = f2bf(a.z);
    t[c4*4+3][row] = f2bf(a.w);
  }
  __syncthreads();
#pragma unroll
  for (int r = 0; r < 4; ++r) {
    int slot = r * 256 + tid;
    int row = slot >> 4, c4 = slot & 15;
    uint2 v;
    v.x = t[row][c4*4+0] | ((unsigned)t[row][c4*4+1] << 16);
    v.y = t[row][c4*4+2] | ((unsigned)t[row][c4*4+3] << 16);
    *(uint2*)(dst + (long)(n0 + row) * 1024 + k0 + c4 * 4) = v;
  }
}

// ---------------------------------------------------------------------------
// m97-style GEMM mainloop (unchanged).
// ---------------------------------------------------------------------------
__device__ __forceinline__ void gemm_main_128x128(
    const u16* __restrict__ A, const u16* __restrict__ BT,
    u16* lA, u16* lB, int m0, int n0, int tid, f32x4 acc[4][4])
{
  int w = tid >> 6, l = tid & 63, quad = l >> 4, lm = l & 15;
  int wm = w >> 1, wn = w & 1;
  int srow = tid >> 2, schunk = tid & 3;
  int sxw = (srow >> 1) & 3;
  int sxr = (lm >> 1) & 3;
  const u16* Ag = A + (long)(m0 + srow) * 1024 + (schunk ^ sxw) * 8;
  const u16* Bg = BT + (long)(n0 + srow) * 1024 + (schunk ^ sxw) * 8;
  u16* lAw = lA + w * 512;
  u16* lBw = lB + w * 512;
  for (int kb = 0; kb < 32; ++kb) {
    const u16* Agk = Ag + kb * 32;
    const u16* Bgk = Bg + kb * 32;
    __builtin_amdgcn_global_load_lds(AS1(Agk),           AS3(lAw),        16, 0, 0);
    __builtin_amdgcn_global_load_lds(AS1(Agk + 64*1024), AS3(lAw + 2048), 16, 0, 0);
    __builtin_amdgcn_global_load_lds(AS1(Bgk),           AS3(lBw),        16, 0, 0);
    __builtin_amdgcn_global_load_lds(AS1(Bgk + 64*1024), AS3(lBw + 2048), 16, 0, 0);
    __syncthreads();
    bf16x8 af[4], bfr[4];
#pragma unroll
    for (int mi = 0; mi < 4; ++mi)
      af[mi] = *(const bf16x8*)(lA + (wm*64 + mi*16 + lm)*32 + ((quad ^ sxr))*8);
#pragma unroll
    for (int ni = 0; ni < 4; ++ni)
      bfr[ni] = *(const bf16x8*)(lB + (wn*64 + ni*16 + lm)*32 + ((quad ^ sxr))*8);
#pragma unroll
    for (int mi = 0; mi < 4; ++mi)
#pragma unroll
      for (int ni = 0; ni < 4; ++ni)
        acc[mi][ni] = __builtin_amdgcn_mfma_f32_16x16x32_bf16(af[mi], bfr[ni], acc[mi][ni], 0, 0, 0);
    __syncthreads();
  }
}

// ---------------------------------------------------------------------------
// QKV projection v2 (unchanged).
// ---------------------------------------------------------------------------
__global__ __launch_bounds__(256, 3)
void k_gemm_qkv(const u16* __restrict__ qb, const u16* __restrict__ kvb,
                const u16* __restrict__ wt,
                const float* __restrict__ bq, const float* __restrict__ bk,
                const float* __restrict__ bv,
                u16* __restrict__ Qb, u16* __restrict__ Kb, u16* __restrict__ VTb)
{
  __shared__ u16 lA[4096], lB[4096];
  int tid = threadIdx.x;
  int z = blockIdx.z;
  f32x4 acc[4][4] = {};
  int w = tid >> 6, l = tid & 63, quad = l >> 4, lm = l & 15;
  int wm = w >> 1, wn = w & 1;

  if (z == 2) {
    int m0 = blockIdx.y * 128, n0 = blockIdx.x * 128;
    gemm_main_128x128(kvb, wt + 2 * SZ_W, lA, lB, m0, n0, tid, acc);
#pragma unroll
    for (int ni = 0; ni < 4; ++ni) {
      int n = n0 + wn*64 + ni*16 + lm;       // channel
      float bb = bv[n];
      int h = n >> 7, dd = n & 127;
#pragma unroll
      for (int mi = 0; mi < 4; ++mi) {
        int mbase = m0 + wm*64 + mi*16 + quad*4;  // token (4 consecutive)
        int bidx = mbase >> 11, nn = mbase & 2047;
        u16 o0 = f2bf(acc[mi][ni][0] + bb), o1 = f2bf(acc[mi][ni][1] + bb);
        u16 o2 = f2bf(acc[mi][ni][2] + bb), o3 = f2bf(acc[mi][ni][3] + bb);
        uint2 v; v.x = o0 | ((unsigned)o1 << 16); v.y = o2 | ((unsigned)o3 << 16);
        *(uint2*)(VTb + ((long)(bidx*8 + h)*128 + dd)*2048 + nn) = v;
      }
    }
  } else {
    const u16* X = (z == 0) ? qb : kvb;
    const float* bias = (z == 0) ? bq : bk;
    u16* dst = (z == 0) ? Qb : Kb;
    float scale = (z == 0) ? 0.08838834764831845f : 1.0f;  // fold 1/sqrt(128)
    int m0 = blockIdx.x * 128, n0 = blockIdx.y * 128;
    gemm_main_128x128(wt + (long)z * SZ_W, X, lA, lB, m0, n0, tid, acc);
#pragma unroll
    for (int mi = 0; mi < 4; ++mi) {
      int chb = m0 + wm*64 + mi*16 + quad*4;   // channel base (4 consecutive)
      int h = chb >> 7, d = chb & 127;
      float4 bb = *(const float4*)(bias + chb);
#pragma unroll
      for (int ni = 0; ni < 4; ++ni) {
        int tok = n0 + wn*64 + ni*16 + lm;
        int bidx = tok >> 11, nn = tok & 2047;
        u16 o0 = f2bf((acc[mi][ni][0] + bb.x) * scale);
        u16 o1 = f2bf((acc[mi][ni][1] + bb.y) * scale);
        u16 o2 = f2bf((acc[mi][ni][2] + bb.z) * scale);
        u16 o3 = f2bf((acc[mi][ni][3] + bb.w) * scale);
        uint2 v; v.x = o0 | ((unsigned)o1 << 16); v.y = o2 | ((unsigned)o3 << 16);
        *(uint2*)(dst + ((long)(bidx*8 + h)*2048 + nn)*128 + d) = v;
      }
    }
  }
}

// ---------------------------------------------------------------------------
// Flash attention v16 — v15 + T12 in-register softmax (swapped QK^T).
//
// v15 (56.7us) == v13 (57.8) == v11 (62.2) despite wildly different LDS/MFMA
// mixes -> the shared per-tile serialized spine binds: barrier -> kf lgkm ->
// QK chain -> softmax with P LDS write->read round-trip (2 more lgkm stalls)
// -> PV -> barrier, at 2 waves/SIMD.
//
// v16 removes the P round-trip entirely (T12): QK^T operands SWAPPED
// (mfma(kf, qf): A=K row=key=c31, B=Q col=q=c31 -- same frag layouts, just
// swapped args). D now holds S[key R(g,l5)][q=c31] per lane. Softmax is
// fully in-register (per-lane scalar row-sum; one shfl_xor(32) at kernel
// end). P->PV A-frags built in-register: 8 pkbf words own[G][w] (G=g>>2)
// + per-ks 2-word shfl_xor(32) half-exchange. Index algebra (HW D-layout
// row=(g&3)+8(g>>2)+4*l5): pa[ks] elem e = P[q=c31][key ks*16+l5*8+e];
// producer of key K* is half h=(K*>>2)&1, word source own[G=K*>>3][(K*&3)>>1].
// Deleted per wave/tile: 16 ds_write_b16 + 2 ds_read_b128 + 2 lgkm
// round-trips + ~48 f2bf VALU. Added: 8 pkbf + 4 shfl + 8 cndmask.
// lP freed: LDS 85 -> 65 KB. All own[] indices static or ternary (rule #20).
// K/V staging, swizzles, PV, merge: v15-identical.
// LDS u16: bufK 2x8192 [0,16384) | bufV 2x8192 [16384,32768) | lStat 512
// [32768,33280) = 65 KB. lO (64 KB f32) overlays bufK/V after the loop.
// ---------------------------------------------------------------------------
__global__ __launch_bounds__(512, 2)
void k_attn(const u16* __restrict__ Qb, const u16* __restrict__ Kb,
            const u16* __restrict__ VTb, u16* __restrict__ Sout)
{
  __shared__ u16 smem[33280];   // 65 KB
  float* lStat = (float*)(smem + 32768);  // [4 qg][2 kh][32 q]

  int tid = threadIdx.x;
  int w = tid >> 6, l = tid & 63;
  int l5 = l >> 5, c31 = l & 31;
  int qg = w >> 1, kh = w & 1;
  int bh = blockIdx.x;             // XCD = bh % 8 -> 2 bh per XCD L2
  int q0 = blockIdx.y * 128 + qg * 32;
  const u16* Qg = Qb + ((long)bh * 2048 + q0) * 128;
  const u16* Kg = Kb + (long)bh * 2048 * 128;
  const u16* Vg = VTb + (long)bh * 128 * 2048;

  // register-resident Q: qf[c] = Q[q=c31][d = c*16 + l5*8 + j]
  bf16x8 qf[8];
#pragma unroll
  for (int c = 0; c < 8; ++c)
    qf[c] = *(const bf16x8*)(Qg + (long)c31 * 128 + c*16 + l5*8);

  f32x16 accO[4] = {};   // [dtile]; row=q via R(g,l5), col=d=dtile*32+c31
  float sumP = 0.f;      // per-lane: q=c31, own 16 keys/tile, all tiles

  // Cooperative staging of a 64-key tile (1024 x 16B chunks each for K,V);
  // 512 lanes x 2 DMA each. Dest lane-linear; swizzle on global src (m173).
  auto stage = [&](int tt) {
    int bufK = (tt & 1) * 8192;
    int bufV = 16384 + (tt & 1) * 8192;
#pragma unroll
    for (int j = 0; j < 2; ++j) {
      int s = j*512 + tid;             // 0..1023
      int r = s >> 4, sl = s & 15;     // key row 0..63, stored slot
      __builtin_amdgcn_global_load_lds(
          AS1(Kg + (long)(tt*64 + r)*128 + ((sl ^ (r & 15)) * 8)),
          AS3(smem + bufK + (j*512 + w*64)*8), 16, 0, 0);
    }
#pragma unroll
    for (int j = 0; j < 2; ++j) {
      int s = j*512 + tid;             // 0..1023
      int d = s >> 3, sl = s & 7;      // d row 0..127, stored slot
      __builtin_amdgcn_global_load_lds(
          AS1(Vg + (long)d*2048 + tt*64 + ((sl ^ (d & 7)) * 8)),
          AS3(smem + bufV + (j*512 + w*64)*8), 16, 0, 0);
    }
  };

  stage(0);

#pragma unroll 1
  for (int t = 0; t < 32; ++t) {
    __syncthreads();          // drains stage(t) DMA; WAR-protects buf (t+1)&1
    if (t < 31) stage(t + 1);

    const u16* bK = smem + (t & 1) * 8192;
    const u16* bV = smem + 16384 + (t & 1) * 8192;

    // QK^T SWAPPED: accS = K_half x Q -> S[key][q]; 8 MFMAs, 2 acc chains.
    f32x16 accS[2] = {};
#pragma unroll
    for (int c = 0; c < 8; ++c) {
      int r = kh*32 + c31;                       // lane's key row (A row)
      bf16x8 kf = *(const bf16x8*)(bK + (r*16 + ((2*c + l5) ^ (l & 15)))*8);
      accS[c & 1] = __builtin_amdgcn_mfma_f32_32x32x16_bf16(kf, qf[c], accS[c & 1], 0, 0, 0);
    }

    // in-register softmax: p=exp(s); pack own[G][w] bf16 pairs (keys
    // 8G+4*l5+{0..3} for q=c31); per-lane scalar row-sum.
    unsigned own0[2], own1[2], own2[2], own3[2];
    {
      float ss = 0.f;
#pragma unroll
      for (int G = 0; G < 4; ++G) {
        float p0 = __expf(accS[0][4*G+0] + accS[1][4*G+0]);
        float p1 = __expf(accS[0][4*G+1] + accS[1][4*G+1]);
        float p2 = __expf(accS[0][4*G+2] + accS[1][4*G+2]);
        float p3 = __expf(accS[0][4*G+3] + accS[1][4*G+3]);
        ss += (p0 + p1) + (p2 + p3);
        unsigned wa = pkbf(p0, p1), wb = pkbf(p2, p3);
        if (G == 0) { own0[0] = wa; own0[1] = wb; }
        if (G == 1) { own1[0] = wa; own1[1] = wb; }
        if (G == 2) { own2[0] = wa; own2[1] = wb; }
        if (G == 3) { own3[0] = wa; own3[1] = wb; }
      }
      sumP += ss;
    }

    // PV: per ks, assemble pa (A-frag, row=q) via 2-word half-exchange.
#pragma unroll
    for (int ks = 0; ks < 2; ++ks) {
      // xfer = own[2*ks + (1-l5)]  (static-index ternary, no scratch)
      unsigned xa, xb;
      if (ks == 0) { xa = l5 ? own0[0] : own1[0]; xb = l5 ? own0[1] : own1[1]; }
      else         { xa = l5 ? own2[0] : own3[0]; xb = l5 ? own2[1] : own3[1]; }
      unsigned ra = __shfl_xor((int)xa, 32);
      unsigned rb = __shfl_xor((int)xb, 32);
      uint4 uw;
      if (ks == 0) {
        uw.x = l5 ? ra : own0[0];  uw.y = l5 ? rb : own0[1];
        uw.z = l5 ? own1[0] : ra;  uw.w = l5 ? own1[1] : rb;
      } else {
        uw.x = l5 ? ra : own2[0];  uw.y = l5 ? rb : own2[1];
        uw.z = l5 ? own3[0] : ra;  uw.w = l5 ? own3[1] : rb;
      }
      bf16x8 pa = __builtin_bit_cast(bf16x8, uw);
#pragma unroll
      for (int dt = 0; dt < 4; ++dt) {
        int d = dt*32 + c31;
        int cc = kh*4 + ks*2 + l5;               // logical key-chunk in d-row
        bf16x8 vf = *(const bf16x8*)(bV + (d*8 + (cc ^ (d & 7)))*8);
        accO[dt] = __builtin_amdgcn_mfma_f32_32x32x16_bf16(pa, vf, accO[dt], 0, 0, 0);
      }
    }
  }

  // ---- finalize row sums: add the complementary 16-key half per q=c31 ----
  {
    float s = sumP;
    s += __shfl_xor(s, 32);
    lStat[(qg*2 + kh)*32 + c31] = s;   // both halves same value: benign dup
  }

  // ---- pair merge: kh=1 parks unnormalized O, kh=0 combines ----
  float* lO = (float*)smem;   // [4 qg][32 q][128 d] f32 = 64 KB over bufK/V
  __syncthreads();            // all tile reads done; lStat visible
  if (kh == 1) {
#pragma unroll
    for (int dt = 0; dt < 4; ++dt)
#pragma unroll
      for (int g = 0; g < 16; ++g) {
        int R = (g & 3) + 8*(g >> 2) + 4*l5;
        lO[(qg*32 + R)*128 + dt*32 + c31] = accO[dt][g];
      }
  }
  __syncthreads();
  if (kh == 0) {
    int b = bh >> 3, h = bh & 7;
#pragma unroll
    for (int g = 0; g < 16; ++g) {
      int R = (g & 3) + 8*(g >> 2) + 4*l5;
      float linv = 1.f / (lStat[(qg*2)*32 + R] + lStat[(qg*2 + 1)*32 + R]);
#pragma unroll
      for (int dt = 0; dt < 4; ++dt) {
        float v = (accO[dt][g] + lO[(qg*32 + R)*128 + dt*32 + c31]) * linv;
        Sout[((long)(b*2048 + q0 + R))*1024 + h*128 + dt*32 + c31] = f2bf(v);
      }
    }
  }
}

// ---------------------------------------------------------------------------
// Output projection v2 (unchanged).
// ---------------------------------------------------------------------------
__global__ __launch_bounds__(256, 3)
void k_gemm_out(const u16* __restrict__ S, const u16* __restrict__ WoT,
                const float* __restrict__ bo, float* __restrict__ out)
{
  __shared__ u16 lA[4096], lB[4096];
  int tid = threadIdx.x;
  int m0 = blockIdx.x * 128, n0 = blockIdx.y * 128;   // m = channel, n = token
  f32x4 acc[4][4] = {};
  gemm_main_128x128(WoT, S, lA, lB, m0, n0, tid, acc);

  int w = tid >> 6, l = tid & 63, quad = l >> 4, lm = l & 15;
  int wm = w >> 1, wn = w & 1;
#pragma unroll
  for (int mi = 0; mi < 4; ++mi) {
    int chb = m0 + wm*64 + mi*16 + quad*4;   // 4 consecutive channels
    float4 bb = *(const float4*)(bo + chb);
#pragma unroll
    for (int ni = 0; ni < 4; ++ni) {
      int tok = n0 + wn*64 + ni*16 + lm;
      float4 v;
      v.x = acc[mi][ni][0] + bb.x;
      v.y = acc[mi][ni][1] + bb.y;
      v.z = acc[mi][ni][2] + bb.z;
      v.w = acc[mi][ni][3] + bb.w;
      *(float4*)(out + (long)tok * 1024 + chb) = v;
    }
  }
}

// ---------------------------------------------------------------------------
// ws layout (u16 elems), 48 MiB: ABUF (q_bf16, reused for summed), KVB,
// WT 4x, Qb/Kb [b][h][n][d], VTb [b][h][d][n]
// ---------------------------------------------------------------------------
extern "C" void kernel_launch(void* const* d_in, const int* in_sizes, int n_in,
                              void* d_out, int out_size, void* d_ws, size_t ws_size,
                              hipStream_t stream)
{
  const float* inq  = (const float*)d_in[0];
  const float* inkv = (const float*)d_in[1];
  const float* Wq = (const float*)d_in[2];
  const float* bq = (const float*)d_in[3];
  const float* Wk = (const float*)d_in[4];
  const float* bk = (const float*)d_in[5];
  const float* Wv = (const float*)d_in[6];
  const float* bv = (const float*)d_in[7];
  const float* Wo = (const float*)d_in[8];
  const float* bo = (const float*)d_in[9];

  u16* ws   = (u16*)d_ws;
  u16* ABUF = ws;
  u16* KVB  = ws + SZ_IN;
  u16* WT   = ws + 2 * SZ_IN;
  u16* Qb   = WT + 4 * SZ_W;
  u16* Kb   = Qb + SZ_IN;
  u16* VTb  = Kb + SZ_IN;

  k_cast    <<<dim3(2048, 3),   256, 0, stream>>>(inq, inkv, Wq, Wk, Wv, Wo, ABUF, KVB, WT);
  k_gemm_qkv<<<dim3(8, 32, 3),  256, 0, stream>>>(ABUF, KVB, WT, bq, bk, bv, Qb, Kb, VTb);
  k_attn    <<<dim3(16, 16),    512, 0, stream>>>(Qb, Kb, VTb, ABUF);
  k_gemm_out<<<dim3(8, 32),     256, 0, stream>>>(ABUF, WT + 3 * SZ_W, bo, (float*)d_out);
}

// Round 9
// 211.101 us; speedup vs baseline: 1.0352x; 1.0065x over previous
//
#include <hip/hip_runtime.h>

typedef unsigned short u16;
typedef __bf16 bf16;
typedef __attribute__((ext_vector_type(8))) __bf16 bf16x8;   // MFMA A/B frag (4 VGPRs)
typedef __attribute__((ext_vector_type(4))) float f32x4;     // 16x16 MFMA C/D frag
typedef __attribute__((ext_vector_type(16))) float f32x16;   // 32x32 MFMA C/D frag

#define AS1(p) ((const __attribute__((address_space(1))) void*)(p))
#define AS3(p) ((__attribute__((address_space(3))) void*)(p))

__device__ __forceinline__ u16 f2bf(float f) {
  unsigned u = __builtin_bit_cast(unsigned, f);
  u += 0x7fffu + ((u >> 16) & 1u);
  return (u16)(u >> 16);
}

// packed bf16 pair (RNE via compiler bf16 casts; may fuse to v_cvt_pk_bf16_f32)
__device__ __forceinline__ unsigned pkbf(float a, float b) {
  unsigned lo = (unsigned)__builtin_bit_cast(unsigned short, (__bf16)a);
  unsigned hi = (unsigned)__builtin_bit_cast(unsigned short, (__bf16)b);
  return lo | (hi << 16);
}

static constexpr int  B_ = 2, N_ = 2048, C_ = 1024, H_ = 8, DH_ = 128;
static constexpr long SZ_IN = (long)B_ * N_ * C_;  // 4,194,304 elems
static constexpr long SZ_W  = (long)C_ * C_;       // 1,048,576 elems

// ---------------------------------------------------------------------------
// Fused cast kernel (unchanged).
// ---------------------------------------------------------------------------
__global__ void k_cast(const float* __restrict__ q, const float* __restrict__ kv,
                       const float* __restrict__ W0, const float* __restrict__ W1,
                       const float* __restrict__ W2, const float* __restrict__ W3,
                       u16* __restrict__ qb, u16* __restrict__ kvb,
                       u16* __restrict__ WT)
{
  __shared__ u16 t[64][65];
  int tid = threadIdx.x;
  if (blockIdx.y < 2) {
    const float* src = blockIdx.y ? kv : q;
    u16* dst = blockIdx.y ? kvb : qb;
    long i = ((long)blockIdx.x * 256 + tid) * 8;
    float4 a = *(const float4*)(src + i);
    float4 b = *(const float4*)(src + i + 4);
    uint4 v;
    v.x = f2bf(a.x) | ((unsigned)f2bf(a.y) << 16);
    v.y = f2bf(a.z) | ((unsigned)f2bf(a.w) << 16);
    v.z = f2bf(b.x) | ((unsigned)f2bf(b.y) << 16);
    v.w = f2bf(b.z) | ((unsigned)f2bf(b.w) << 16);
    *(uint4*)(dst + i) = v;
    return;
  }
  int x = blockIdx.x;
  if (x >= 1024) return;
  int z = x >> 8, tile = x & 255;
  const float* W = (z == 0) ? W0 : (z == 1) ? W1 : (z == 2) ? W2 : W3;
  u16* dst = WT + (long)z * SZ_W;
  int n0 = (tile & 15) * 64, k0 = (tile >> 4) * 64;
#pragma unroll
  for (int r = 0; r < 4; ++r) {
    int slot = r * 256 + tid;
    int row = slot >> 4, c4 = slot & 15;
    float4 a = *(const float4*)(W + (long)(k0 + row) * 1024 + n0 + c4 * 4);
    t[c4*4+0][row] = f2bf(a.x);
    t[c4*4+1][row] = f2bf(a.y);
    t[c4*4+2][row] = f2bf(a.z);
    t[c4*4+3][row] = f2bf(a.w);
  }
  __syncthreads();
#pragma unroll
  for (int r = 0; r < 4; ++r) {
    int slot = r * 256 + tid;
    int row = slot >> 4, c4 = slot & 15;
    uint2 v;
    v.x = t[row][c4*4+0] | ((unsigned)t[row][c4*4+1] << 16);
    v.y = t[row][c4*4+2] | ((unsigned)t[row][c4*4+3] << 16);
    *(uint2*)(dst + (long)(n0 + row) * 1024 + k0 + c4 * 4) = v;
  }
}

// ---------------------------------------------------------------------------
// m97-style GEMM mainloop (unchanged).
// ---------------------------------------------------------------------------
__device__ __forceinline__ void gemm_main_128x128(
    const u16* __restrict__ A, const u16* __restrict__ BT,
    u16* lA, u16* lB, int m0, int n0, int tid, f32x4 acc[4][4])
{
  int w = tid >> 6, l = tid & 63, quad = l >> 4, lm = l & 15;
  int wm = w >> 1, wn = w & 1;
  int srow = tid >> 2, schunk = tid & 3;
  int sxw = (srow >> 1) & 3;
  int sxr = (lm >> 1) & 3;
  const u16* Ag = A + (long)(m0 + srow) * 1024 + (schunk ^ sxw) * 8;
  const u16* Bg = BT + (long)(n0 + srow) * 1024 + (schunk ^ sxw) * 8;
  u16* lAw = lA + w * 512;
  u16* lBw = lB + w * 512;
  for (int kb = 0; kb < 32; ++kb) {
    const u16* Agk = Ag + kb * 32;
    const u16* Bgk = Bg + kb * 32;
    __builtin_amdgcn_global_load_lds(AS1(Agk),           AS3(lAw),        16, 0, 0);
    __builtin_amdgcn_global_load_lds(AS1(Agk + 64*1024), AS3(lAw + 2048), 16, 0, 0);
    __builtin_amdgcn_global_load_lds(AS1(Bgk),           AS3(lBw),        16, 0, 0);
    __builtin_amdgcn_global_load_lds(AS1(Bgk + 64*1024), AS3(lBw + 2048), 16, 0, 0);
    __syncthreads();
    bf16x8 af[4], bfr[4];
#pragma unroll
    for (int mi = 0; mi < 4; ++mi)
      af[mi] = *(const bf16x8*)(lA + (wm*64 + mi*16 + lm)*32 + ((quad ^ sxr))*8);
#pragma unroll
    for (int ni = 0; ni < 4; ++ni)
      bfr[ni] = *(const bf16x8*)(lB + (wn*64 + ni*16 + lm)*32 + ((quad ^ sxr))*8);
#pragma unroll
    for (int mi = 0; mi < 4; ++mi)
#pragma unroll
      for (int ni = 0; ni < 4; ++ni)
        acc[mi][ni] = __builtin_amdgcn_mfma_f32_16x16x32_bf16(af[mi], bfr[ni], acc[mi][ni], 0, 0, 0);
    __syncthreads();
  }
}

// ---------------------------------------------------------------------------
// QKV projection v2 (unchanged).
// ---------------------------------------------------------------------------
__global__ __launch_bounds__(256, 3)
void k_gemm_qkv(const u16* __restrict__ qb, const u16* __restrict__ kvb,
                const u16* __restrict__ wt,
                const float* __restrict__ bq, const float* __restrict__ bk,
                const float* __restrict__ bv,
                u16* __restrict__ Qb, u16* __restrict__ Kb, u16* __restrict__ VTb)
{
  __shared__ u16 lA[4096], lB[4096];
  int tid = threadIdx.x;
  int z = blockIdx.z;
  f32x4 acc[4][4] = {};
  int w = tid >> 6, l = tid & 63, quad = l >> 4, lm = l & 15;
  int wm = w >> 1, wn = w & 1;

  if (z == 2) {
    int m0 = blockIdx.y * 128, n0 = blockIdx.x * 128;
    gemm_main_128x128(kvb, wt + 2 * SZ_W, lA, lB, m0, n0, tid, acc);
#pragma unroll
    for (int ni = 0; ni < 4; ++ni) {
      int n = n0 + wn*64 + ni*16 + lm;       // channel
      float bb = bv[n];
      int h = n >> 7, dd = n & 127;
#pragma unroll
      for (int mi = 0; mi < 4; ++mi) {
        int mbase = m0 + wm*64 + mi*16 + quad*4;  // token (4 consecutive)
        int bidx = mbase >> 11, nn = mbase & 2047;
        u16 o0 = f2bf(acc[mi][ni][0] + bb), o1 = f2bf(acc[mi][ni][1] + bb);
        u16 o2 = f2bf(acc[mi][ni][2] + bb), o3 = f2bf(acc[mi][ni][3] + bb);
        uint2 v; v.x = o0 | ((unsigned)o1 << 16); v.y = o2 | ((unsigned)o3 << 16);
        *(uint2*)(VTb + ((long)(bidx*8 + h)*128 + dd)*2048 + nn) = v;
      }
    }
  } else {
    const u16* X = (z == 0) ? qb : kvb;
    const float* bias = (z == 0) ? bq : bk;
    u16* dst = (z == 0) ? Qb : Kb;
    float scale = (z == 0) ? 0.08838834764831845f : 1.0f;  // fold 1/sqrt(128)
    int m0 = blockIdx.x * 128, n0 = blockIdx.y * 128;
    gemm_main_128x128(wt + (long)z * SZ_W, X, lA, lB, m0, n0, tid, acc);
#pragma unroll
    for (int mi = 0; mi < 4; ++mi) {
      int chb = m0 + wm*64 + mi*16 + quad*4;   // channel base (4 consecutive)
      int h = chb >> 7, d = chb & 127;
      float4 bb = *(const float4*)(bias + chb);
#pragma unroll
      for (int ni = 0; ni < 4; ++ni) {
        int tok = n0 + wn*64 + ni*16 + lm;
        int bidx = tok >> 11, nn = tok & 2047;
        u16 o0 = f2bf((acc[mi][ni][0] + bb.x) * scale);
        u16 o1 = f2bf((acc[mi][ni][1] + bb.y) * scale);
        u16 o2 = f2bf((acc[mi][ni][2] + bb.z) * scale);
        u16 o3 = f2bf((acc[mi][ni][3] + bb.w) * scale);
        uint2 v; v.x = o0 | ((unsigned)o1 << 16); v.y = o2 | ((unsigned)o3 << 16);
        *(uint2*)(dst + ((long)(bidx*8 + h)*2048 + nn)*128 + d) = v;
      }
    }
  }
}

// ---------------------------------------------------------------------------
// Flash attention v17 — v16 + loop-invariant addressing (VALU hoist).
//
// v16 (57.0us): VALUBusy 34.9 is now the LARGEST pipe (MfmaUtil 25.1). At 2
// barrier-locked waves/SIMD the pipes serialize: MFMA 1024 + VALU ~1500 +
// LDS ~400 + stalls = observed 4275 cy/tile/SIMD. ~2/3 of the VALU is
// per-tile recomputation of per-lane LDS addresses (kf: (r*16+((2c+l5)^
// (l&15)))*16 x8; vf x8; staging addr from tt) that is LOOP-INVARIANT per
// lane except the buffer-parity term.
//
// v17: (1) precompute offK[8]/offV[2][4] per-lane byte offsets before the
// loop; all bases {0,16384,32768,49152}+off < 65536 fit the 16-bit ds_read
// offset: immediate. (2) unroll tile loop x2 so buffer parity is compile-
// time -> ds_read_b128 v, off[c] offset:IMM, zero per-tile addr VALU.
// (3) staging src = 4 persistent per-lane pointers += one tile-stride per
// stage; LDS dest base literal. Everything else (swapped QK^T, in-register
// softmax, half-exchange PV, pair merge) v16-identical.
// LDS u16: bufK 2x8192 [0,16384) | bufV 2x8192 [16384,32768) | lStat 512
// [32768,33280) = 65 KB. lO (64 KB f32) overlays bufK/V after the loop.
// ---------------------------------------------------------------------------
__global__ __launch_bounds__(512, 2)
void k_attn(const u16* __restrict__ Qb, const u16* __restrict__ Kb,
            const u16* __restrict__ VTb, u16* __restrict__ Sout)
{
  __shared__ u16 smem[33280];   // 65 KB
  float* lStat = (float*)(smem + 32768);  // [4 qg][2 kh][32 q]

  int tid = threadIdx.x;
  int w = tid >> 6, l = tid & 63;
  int l5 = l >> 5, c31 = l & 31;
  int qg = w >> 1, kh = w & 1;
  int bh = blockIdx.x;             // XCD = bh % 8 -> 2 bh per XCD L2
  int q0 = blockIdx.y * 128 + qg * 32;
  const u16* Qg = Qb + ((long)bh * 2048 + q0) * 128;
  const u16* Kg = Kb + (long)bh * 2048 * 128;
  const u16* Vg = VTb + (long)bh * 128 * 2048;

  // register-resident Q: qf[c] = Q[q=c31][d = c*16 + l5*8 + j]
  bf16x8 qf[8];
#pragma unroll
  for (int c = 0; c < 8; ++c)
    qf[c] = *(const bf16x8*)(Qg + (long)c31 * 128 + c*16 + l5*8);

  // ---- loop-invariant per-lane LDS byte offsets (fit ds_read imm+off) ----
  int offK[8];
#pragma unroll
  for (int c = 0; c < 8; ++c) {
    int r = kh*32 + c31;
    offK[c] = (r*16 + ((2*c + l5) ^ (l & 15))) * 16;       // < 16384
  }
  int offV[2][4];
#pragma unroll
  for (int ks = 0; ks < 2; ++ks)
#pragma unroll
    for (int dt = 0; dt < 4; ++dt) {
      int d = dt*32 + c31;
      int cc = kh*4 + ks*2 + l5;
      offV[ks][dt] = (d*8 + (cc ^ (d & 7))) * 16;          // < 16384
    }

  // ---- persistent staging src pointers (advance one tile per stage) ----
  const u16* sK[2];
  const u16* sV[2];
#pragma unroll
  for (int j = 0; j < 2; ++j) {
    int s = j*512 + tid;             // 0..1023
    int r = s >> 4, sl = s & 15;     // key row 0..63, stored slot
    sK[j] = Kg + (long)r*128 + ((sl ^ (r & 15)) * 8);
    int d = s >> 3, sv = s & 7;      // d row 0..127, stored slot
    sV[j] = Vg + (long)d*2048 + ((sv ^ (d & 7)) * 8);
  }

  f32x16 accO[4] = {};   // [dtile]; row=q via R(g,l5), col=d=dtile*32+c31
  float sumP = 0.f;      // per-lane: q=c31, own 16 keys/tile, all tiles

  const char* smemB = (const char*)smem;

  // stage next tile into buffer at u16-elem offset bufe (0 or 8192)
  auto stageTo = [&](int bufe) {
#pragma unroll
    for (int j = 0; j < 2; ++j) {
      __builtin_amdgcn_global_load_lds(AS1(sK[j]),
          AS3(smem + bufe + (j*512 + w*64)*8), 16, 0, 0);
      sK[j] += 64*128;   // one 64-key tile forward
    }
#pragma unroll
    for (int j = 0; j < 2; ++j) {
      __builtin_amdgcn_global_load_lds(AS1(sV[j]),
          AS3(smem + 16384 + bufe + (j*512 + w*64)*8), 16, 0, 0);
      sV[j] += 64;       // one 64-key tile forward (row-major stride 2048)
    }
  };

  // compute one 64-key tile from buffers at byte imm KIMM/VIMM (literals)
  auto computeTile = [&](int KIMM, int VIMM) {
    // QK^T SWAPPED: accS = K_half x Q -> S[key][q]; 8 MFMAs, 2 acc chains.
    f32x16 accS[2] = {};
#pragma unroll
    for (int c = 0; c < 8; ++c) {
      bf16x8 kf = *(const bf16x8*)(smemB + KIMM + offK[c]);
      accS[c & 1] = __builtin_amdgcn_mfma_f32_32x32x16_bf16(kf, qf[c], accS[c & 1], 0, 0, 0);
    }

    // in-register softmax: p=exp(s); pack own[G][w] bf16 pairs.
    unsigned own0[2], own1[2], own2[2], own3[2];
    {
      float ss = 0.f;
#pragma unroll
      for (int G = 0; G < 4; ++G) {
        float p0 = __expf(accS[0][4*G+0] + accS[1][4*G+0]);
        float p1 = __expf(accS[0][4*G+1] + accS[1][4*G+1]);
        float p2 = __expf(accS[0][4*G+2] + accS[1][4*G+2]);
        float p3 = __expf(accS[0][4*G+3] + accS[1][4*G+3]);
        ss += (p0 + p1) + (p2 + p3);
        unsigned wa = pkbf(p0, p1), wb = pkbf(p2, p3);
        if (G == 0) { own0[0] = wa; own0[1] = wb; }
        if (G == 1) { own1[0] = wa; own1[1] = wb; }
        if (G == 2) { own2[0] = wa; own2[1] = wb; }
        if (G == 3) { own3[0] = wa; own3[1] = wb; }
      }
      sumP += ss;
    }

    // PV: per ks, assemble pa (A-frag, row=q) via 2-word half-exchange.
#pragma unroll
    for (int ks = 0; ks < 2; ++ks) {
      unsigned xa, xb;
      if (ks == 0) { xa = l5 ? own0[0] : own1[0]; xb = l5 ? own0[1] : own1[1]; }
      else         { xa = l5 ? own2[0] : own3[0]; xb = l5 ? own2[1] : own3[1]; }
      unsigned ra = __shfl_xor((int)xa, 32);
      unsigned rb = __shfl_xor((int)xb, 32);
      uint4 uw;
      if (ks == 0) {
        uw.x = l5 ? ra : own0[0];  uw.y = l5 ? rb : own0[1];
        uw.z = l5 ? own1[0] : ra;  uw.w = l5 ? own1[1] : rb;
      } else {
        uw.x = l5 ? ra : own2[0];  uw.y = l5 ? rb : own2[1];
        uw.z = l5 ? own3[0] : ra;  uw.w = l5 ? own3[1] : rb;
      }
      bf16x8 pa = __builtin_bit_cast(bf16x8, uw);
#pragma unroll
      for (int dt = 0; dt < 4; ++dt) {
        bf16x8 vf = *(const bf16x8*)(smemB + VIMM + offV[ks][dt]);
        accO[dt] = __builtin_amdgcn_mfma_f32_32x32x16_bf16(pa, vf, accO[dt], 0, 0, 0);
      }
    }
  };

  stageTo(0);   // tile 0 -> buf0

#pragma unroll 1
  for (int t = 0; t < 32; t += 2) {
    // even tile: read buf0, prefetch t+1 -> buf1
    __syncthreads();            // drains stage(t) DMA; WAR-protects buf1
    stageTo(8192);              // t+1 <= 31 always (t <= 30)
    computeTile(0, 32768);
    // odd tile: read buf1, prefetch t+2 -> buf0
    __syncthreads();            // drains stage(t+1) DMA; WAR-protects buf0
    if (t + 2 < 32) stageTo(0);
    computeTile(16384, 32768 + 16384);
  }

  // ---- finalize row sums: add the complementary 16-key half per q=c31 ----
  {
    float s = sumP;
    s += __shfl_xor(s, 32);
    lStat[(qg*2 + kh)*32 + c31] = s;   // both halves same value: benign dup
  }

  // ---- pair merge: kh=1 parks unnormalized O, kh=0 combines ----
  float* lO = (float*)smem;   // [4 qg][32 q][128 d] f32 = 64 KB over bufK/V
  __syncthreads();            // all tile reads done; lStat visible
  if (kh == 1) {
#pragma unroll
    for (int dt = 0; dt < 4; ++dt)
#pragma unroll
      for (int g = 0; g < 16; ++g) {
        int R = (g & 3) + 8*(g >> 2) + 4*l5;
        lO[(qg*32 + R)*128 + dt*32 + c31] = accO[dt][g];
      }
  }
  __syncthreads();
  if (kh == 0) {
    int b = bh >> 3, h = bh & 7;
#pragma unroll
    for (int g = 0; g < 16; ++g) {
      int R = (g & 3) + 8*(g >> 2) + 4*l5;
      float linv = 1.f / (lStat[(qg*2)*32 + R] + lStat[(qg*2 + 1)*32 + R]);
#pragma unroll
      for (int dt = 0; dt < 4; ++dt) {
        float v = (accO[dt][g] + lO[(qg*32 + R)*128 + dt*32 + c31]) * linv;
        Sout[((long)(b*2048 + q0 + R))*1024 + h*128 + dt*32 + c31] = f2bf(v);
      }
    }
  }
}

// ---------------------------------------------------------------------------
// Output projection v2 (unchanged).
// ---------------------------------------------------------------------------
__global__ __launch_bounds__(256, 3)
void k_gemm_out(const u16* __restrict__ S, const u16* __restrict__ WoT,
                const float* __restrict__ bo, float* __restrict__ out)
{
  __shared__ u16 lA[4096], lB[4096];
  int tid = threadIdx.x;
  int m0 = blockIdx.x * 128, n0 = blockIdx.y * 128;   // m = channel, n = token
  f32x4 acc[4][4] = {};
  gemm_main_128x128(WoT, S, lA, lB, m0, n0, tid, acc);

  int w = tid >> 6, l = tid & 63, quad = l >> 4, lm = l & 15;
  int wm = w >> 1, wn = w & 1;
#pragma unroll
  for (int mi = 0; mi < 4; ++mi) {
    int chb = m0 + wm*64 + mi*16 + quad*4;   // 4 consecutive channels
    float4 bb = *(const float4*)(bo + chb);
#pragma unroll
    for (int ni = 0; ni < 4; ++ni) {
      int tok = n0 + wn*64 + ni*16 + lm;
      float4 v;
      v.x = acc[mi][ni][0] + bb.x;
      v.y = acc[mi][ni][1] + bb.y;
      v.z = acc[mi][ni][2] + bb.z;
      v.w = acc[mi][ni][3] + bb.w;
      *(float4*)(out + (long)tok * 1024 + chb) = v;
    }
  }
}

// ---------------------------------------------------------------------------
// ws layout (u16 elems), 48 MiB: ABUF (q_bf16, reused for summed), KVB,
// WT 4x, Qb/Kb [b][h][n][d], VTb [b][h][d][n]
// ---------------------------------------------------------------------------
extern "C" void kernel_launch(void* const* d_in, const int* in_sizes, int n_in,
                              void* d_out, int out_size, void* d_ws, size_t ws_size,
                              hipStream_t stream)
{
  const float* inq  = (const float*)d_in[0];
  const float* inkv = (const float*)d_in[1];
  const float* Wq = (const float*)d_in[2];
  const float* bq = (const float*)d_in[3];
  const float* Wk = (const float*)d_in[4];
  const float* bk = (const float*)d_in[5];
  const float* Wv = (const float*)d_in[6];
  const float* bv = (const float*)d_in[7];
  const float* Wo = (const float*)d_in[8];
  const float* bo = (const float*)d_in[9];

  u16* ws   = (u16*)d_ws;
  u16* ABUF = ws;
  u16* KVB  = ws + SZ_IN;
  u16* WT   = ws + 2 * SZ_IN;
  u16* Qb   = WT + 4 * SZ_W;
  u16* Kb   = Qb + SZ_IN;
  u16* VTb  = Kb + SZ_IN;

  k_cast    <<<dim3(2048, 3),   256, 0, stream>>>(inq, inkv, Wq, Wk, Wv, Wo, ABUF, KVB, WT);
  k_gemm_qkv<<<dim3(8, 32, 3),  256, 0, stream>>>(ABUF, KVB, WT, bq, bk, bv, Qb, Kb, VTb);
  k_attn    <<<dim3(16, 16),    512, 0, stream>>>(Qb, Kb, VTb, ABUF);
  k_gemm_out<<<dim3(8, 32),     256, 0, stream>>>(ABUF, WT + 3 * SZ_W, bo, (float*)d_out);
}

// Round 10
// 208.704 us; speedup vs baseline: 1.0471x; 1.0115x over previous
//
#include <hip/hip_runtime.h>

typedef unsigned short u16;
typedef __bf16 bf16;
typedef __attribute__((ext_vector_type(8))) __bf16 bf16x8;   // MFMA A/B frag (4 VGPRs)
typedef __attribute__((ext_vector_type(4))) float f32x4;     // 16x16 MFMA C/D frag
typedef __attribute__((ext_vector_type(16))) float f32x16;   // 32x32 MFMA C/D frag

#define AS1(p) ((const __attribute__((address_space(1))) void*)(p))
#define AS3(p) ((__attribute__((address_space(3))) void*)(p))

__device__ __forceinline__ u16 f2bf(float f) {
  unsigned u = __builtin_bit_cast(unsigned, f);
  u += 0x7fffu + ((u >> 16) & 1u);
  return (u16)(u >> 16);
}

// packed bf16 pair (RNE via compiler bf16 casts; may fuse to v_cvt_pk_bf16_f32)
__device__ __forceinline__ unsigned pkbf(float a, float b) {
  unsigned lo = (unsigned)__builtin_bit_cast(unsigned short, (__bf16)a);
  unsigned hi = (unsigned)__builtin_bit_cast(unsigned short, (__bf16)b);
  return lo | (hi << 16);
}

static constexpr int  B_ = 2, N_ = 2048, C_ = 1024, H_ = 8, DH_ = 128;
static constexpr long SZ_IN = (long)B_ * N_ * C_;  // 4,194,304 elems
static constexpr long SZ_W  = (long)C_ * C_;       // 1,048,576 elems

// ---------------------------------------------------------------------------
// Fused cast kernel (unchanged).
// ---------------------------------------------------------------------------
__global__ void k_cast(const float* __restrict__ q, const float* __restrict__ kv,
                       const float* __restrict__ W0, const float* __restrict__ W1,
                       const float* __restrict__ W2, const float* __restrict__ W3,
                       u16* __restrict__ qb, u16* __restrict__ kvb,
                       u16* __restrict__ WT)
{
  __shared__ u16 t[64][65];
  int tid = threadIdx.x;
  if (blockIdx.y < 2) {
    const float* src = blockIdx.y ? kv : q;
    u16* dst = blockIdx.y ? kvb : qb;
    long i = ((long)blockIdx.x * 256 + tid) * 8;
    float4 a = *(const float4*)(src + i);
    float4 b = *(const float4*)(src + i + 4);
    uint4 v;
    v.x = f2bf(a.x) | ((unsigned)f2bf(a.y) << 16);
    v.y = f2bf(a.z) | ((unsigned)f2bf(a.w) << 16);
    v.z = f2bf(b.x) | ((unsigned)f2bf(b.y) << 16);
    v.w = f2bf(b.z) | ((unsigned)f2bf(b.w) << 16);
    *(uint4*)(dst + i) = v;
    return;
  }
  int x = blockIdx.x;
  if (x >= 1024) return;
  int z = x >> 8, tile = x & 255;
  const float* W = (z == 0) ? W0 : (z == 1) ? W1 : (z == 2) ? W2 : W3;
  u16* dst = WT + (long)z * SZ_W;
  int n0 = (tile & 15) * 64, k0 = (tile >> 4) * 64;
#pragma unroll
  for (int r = 0; r < 4; ++r) {
    int slot = r * 256 + tid;
    int row = slot >> 4, c4 = slot & 15;
    float4 a = *(const float4*)(W + (long)(k0 + row) * 1024 + n0 + c4 * 4);
    t[c4*4+0][row] = f2bf(a.x);
    t[c4*4+1][row] = f2bf(a.y);
    t[c4*4+2][row] = f2bf(a.z);
    t[c4*4+3][row] = f2bf(a.w);
  }
  __syncthreads();
#pragma unroll
  for (int r = 0; r < 4; ++r) {
    int slot = r * 256 + tid;
    int row = slot >> 4, c4 = slot & 15;
    uint2 v;
    v.x = t[row][c4*4+0] | ((unsigned)t[row][c4*4+1] << 16);
    v.y = t[row][c4*4+2] | ((unsigned)t[row][c4*4+3] << 16);
    *(uint2*)(dst + (long)(n0 + row) * 1024 + k0 + c4 * 4) = v;
  }
}

// ---------------------------------------------------------------------------
// m97-style GEMM mainloop (unchanged).
// ---------------------------------------------------------------------------
__device__ __forceinline__ void gemm_main_128x128(
    const u16* __restrict__ A, const u16* __restrict__ BT,
    u16* lA, u16* lB, int m0, int n0, int tid, f32x4 acc[4][4])
{
  int w = tid >> 6, l = tid & 63, quad = l >> 4, lm = l & 15;
  int wm = w >> 1, wn = w & 1;
  int srow = tid >> 2, schunk = tid & 3;
  int sxw = (srow >> 1) & 3;
  int sxr = (lm >> 1) & 3;
  const u16* Ag = A + (long)(m0 + srow) * 1024 + (schunk ^ sxw) * 8;
  const u16* Bg = BT + (long)(n0 + srow) * 1024 + (schunk ^ sxw) * 8;
  u16* lAw = lA + w * 512;
  u16* lBw = lB + w * 512;
  for (int kb = 0; kb < 32; ++kb) {
    const u16* Agk = Ag + kb * 32;
    const u16* Bgk = Bg + kb * 32;
    __builtin_amdgcn_global_load_lds(AS1(Agk),           AS3(lAw),        16, 0, 0);
    __builtin_amdgcn_global_load_lds(AS1(Agk + 64*1024), AS3(lAw + 2048), 16, 0, 0);
    __builtin_amdgcn_global_load_lds(AS1(Bgk),           AS3(lBw),        16, 0, 0);
    __builtin_amdgcn_global_load_lds(AS1(Bgk + 64*1024), AS3(lBw + 2048), 16, 0, 0);
    __syncthreads();
    bf16x8 af[4], bfr[4];
#pragma unroll
    for (int mi = 0; mi < 4; ++mi)
      af[mi] = *(const bf16x8*)(lA + (wm*64 + mi*16 + lm)*32 + ((quad ^ sxr))*8);
#pragma unroll
    for (int ni = 0; ni < 4; ++ni)
      bfr[ni] = *(const bf16x8*)(lB + (wn*64 + ni*16 + lm)*32 + ((quad ^ sxr))*8);
#pragma unroll
    for (int mi = 0; mi < 4; ++mi)
#pragma unroll
      for (int ni = 0; ni < 4; ++ni)
        acc[mi][ni] = __builtin_amdgcn_mfma_f32_16x16x32_bf16(af[mi], bfr[ni], acc[mi][ni], 0, 0, 0);
    __syncthreads();
  }
}

// ---------------------------------------------------------------------------
// QKV projection v3 — v2 + XCD-aware role remap.
//
// Dispatch linear id = x + 8y + 256z -> XCD = x. In v2 the 8 channel-tile
// blocks sharing one 256KB token-panel of X had x=0..7 -> 8 DIFFERENT XCDs:
// every XCD streamed the whole X (8MB qb + 8MB kvb, x3 z) + 6MB weights
// through its 4MB L2 (~190MB aggregate L3/HBM re-reads).
// v3 remap (bijective): channel-tile role bx = y&7, token-panel role
// by = x*4 + (y>>3). All 8 blocks of a token-panel now sit on XCD x; each
// XCD owns 4 complete panels (z=0/1/2 panel ranges coincide -> qb/kvb
// panels shared across z) + weight strips -> L2-resident.
// ---------------------------------------------------------------------------
__global__ __launch_bounds__(256, 3)
void k_gemm_qkv(const u16* __restrict__ qb, const u16* __restrict__ kvb,
                const u16* __restrict__ wt,
                const float* __restrict__ bq, const float* __restrict__ bk,
                const float* __restrict__ bv,
                u16* __restrict__ Qb, u16* __restrict__ Kb, u16* __restrict__ VTb)
{
  __shared__ u16 lA[4096], lB[4096];
  int tid = threadIdx.x;
  int z = blockIdx.z;
  f32x4 acc[4][4] = {};
  int w = tid >> 6, l = tid & 63, quad = l >> 4, lm = l & 15;
  int wm = w >> 1, wn = w & 1;

  // XCD-aware roles: XCD = blockIdx.x; same-token-panel blocks co-XCD.
  int bx = blockIdx.y & 7;                       // channel-tile role [0,8)
  int by = blockIdx.x * 4 + (blockIdx.y >> 3);   // token-panel role [0,32)

  if (z == 2) {
    int m0 = by * 128, n0 = bx * 128;
    gemm_main_128x128(kvb, wt + 2 * SZ_W, lA, lB, m0, n0, tid, acc);
#pragma unroll
    for (int ni = 0; ni < 4; ++ni) {
      int n = n0 + wn*64 + ni*16 + lm;       // channel
      float bb = bv[n];
      int h = n >> 7, dd = n & 127;
#pragma unroll
      for (int mi = 0; mi < 4; ++mi) {
        int mbase = m0 + wm*64 + mi*16 + quad*4;  // token (4 consecutive)
        int bidx = mbase >> 11, nn = mbase & 2047;
        u16 o0 = f2bf(acc[mi][ni][0] + bb), o1 = f2bf(acc[mi][ni][1] + bb);
        u16 o2 = f2bf(acc[mi][ni][2] + bb), o3 = f2bf(acc[mi][ni][3] + bb);
        uint2 v; v.x = o0 | ((unsigned)o1 << 16); v.y = o2 | ((unsigned)o3 << 16);
        *(uint2*)(VTb + ((long)(bidx*8 + h)*128 + dd)*2048 + nn) = v;
      }
    }
  } else {
    const u16* X = (z == 0) ? qb : kvb;
    const float* bias = (z == 0) ? bq : bk;
    u16* dst = (z == 0) ? Qb : Kb;
    float scale = (z == 0) ? 0.08838834764831845f : 1.0f;  // fold 1/sqrt(128)
    int m0 = bx * 128, n0 = by * 128;
    gemm_main_128x128(wt + (long)z * SZ_W, X, lA, lB, m0, n0, tid, acc);
#pragma unroll
    for (int mi = 0; mi < 4; ++mi) {
      int chb = m0 + wm*64 + mi*16 + quad*4;   // channel base (4 consecutive)
      int h = chb >> 7, d = chb & 127;
      float4 bb = *(const float4*)(bias + chb);
#pragma unroll
      for (int ni = 0; ni < 4; ++ni) {
        int tok = n0 + wn*64 + ni*16 + lm;
        int bidx = tok >> 11, nn = tok & 2047;
        u16 o0 = f2bf((acc[mi][ni][0] + bb.x) * scale);
        u16 o1 = f2bf((acc[mi][ni][1] + bb.y) * scale);
        u16 o2 = f2bf((acc[mi][ni][2] + bb.z) * scale);
        u16 o3 = f2bf((acc[mi][ni][3] + bb.w) * scale);
        uint2 v; v.x = o0 | ((unsigned)o1 << 16); v.y = o2 | ((unsigned)o3 << 16);
        *(uint2*)(dst + ((long)(bidx*8 + h)*2048 + nn)*128 + d) = v;
      }
    }
  }
}

// ---------------------------------------------------------------------------
// Flash attention v17 (unchanged, 51.2us round-9-proven).
// ---------------------------------------------------------------------------
__global__ __launch_bounds__(512, 2)
void k_attn(const u16* __restrict__ Qb, const u16* __restrict__ Kb,
            const u16* __restrict__ VTb, u16* __restrict__ Sout)
{
  __shared__ u16 smem[33280];   // 65 KB
  float* lStat = (float*)(smem + 32768);  // [4 qg][2 kh][32 q]

  int tid = threadIdx.x;
  int w = tid >> 6, l = tid & 63;
  int l5 = l >> 5, c31 = l & 31;
  int qg = w >> 1, kh = w & 1;
  int bh = blockIdx.x;             // XCD = bh % 8 -> 2 bh per XCD L2
  int q0 = blockIdx.y * 128 + qg * 32;
  const u16* Qg = Qb + ((long)bh * 2048 + q0) * 128;
  const u16* Kg = Kb + (long)bh * 2048 * 128;
  const u16* Vg = VTb + (long)bh * 128 * 2048;

  // register-resident Q: qf[c] = Q[q=c31][d = c*16 + l5*8 + j]
  bf16x8 qf[8];
#pragma unroll
  for (int c = 0; c < 8; ++c)
    qf[c] = *(const bf16x8*)(Qg + (long)c31 * 128 + c*16 + l5*8);

  // ---- loop-invariant per-lane LDS byte offsets (fit ds_read imm+off) ----
  int offK[8];
#pragma unroll
  for (int c = 0; c < 8; ++c) {
    int r = kh*32 + c31;
    offK[c] = (r*16 + ((2*c + l5) ^ (l & 15))) * 16;       // < 16384
  }
  int offV[2][4];
#pragma unroll
  for (int ks = 0; ks < 2; ++ks)
#pragma unroll
    for (int dt = 0; dt < 4; ++dt) {
      int d = dt*32 + c31;
      int cc = kh*4 + ks*2 + l5;
      offV[ks][dt] = (d*8 + (cc ^ (d & 7))) * 16;          // < 16384
    }

  // ---- persistent staging src pointers (advance one tile per stage) ----
  const u16* sK[2];
  const u16* sV[2];
#pragma unroll
  for (int j = 0; j < 2; ++j) {
    int s = j*512 + tid;             // 0..1023
    int r = s >> 4, sl = s & 15;     // key row 0..63, stored slot
    sK[j] = Kg + (long)r*128 + ((sl ^ (r & 15)) * 8);
    int d = s >> 3, sv = s & 7;      // d row 0..127, stored slot
    sV[j] = Vg + (long)d*2048 + ((sv ^ (d & 7)) * 8);
  }

  f32x16 accO[4] = {};   // [dtile]; row=q via R(g,l5), col=d=dtile*32+c31
  float sumP = 0.f;      // per-lane: q=c31, own 16 keys/tile, all tiles

  const char* smemB = (const char*)smem;

  // stage next tile into buffer at u16-elem offset bufe (0 or 8192)
  auto stageTo = [&](int bufe) {
#pragma unroll
    for (int j = 0; j < 2; ++j) {
      __builtin_amdgcn_global_load_lds(AS1(sK[j]),
          AS3(smem + bufe + (j*512 + w*64)*8), 16, 0, 0);
      sK[j] += 64*128;   // one 64-key tile forward
    }
#pragma unroll
    for (int j = 0; j < 2; ++j) {
      __builtin_amdgcn_global_load_lds(AS1(sV[j]),
          AS3(smem + 16384 + bufe + (j*512 + w*64)*8), 16, 0, 0);
      sV[j] += 64;       // one 64-key tile forward (row-major stride 2048)
    }
  };

  // compute one 64-key tile from buffers at byte imm KIMM/VIMM (literals)
  auto computeTile = [&](int KIMM, int VIMM) {
    // QK^T SWAPPED: accS = K_half x Q -> S[key][q]; 8 MFMAs, 2 acc chains.
    f32x16 accS[2] = {};
#pragma unroll
    for (int c = 0; c < 8; ++c) {
      bf16x8 kf = *(const bf16x8*)(smemB + KIMM + offK[c]);
      accS[c & 1] = __builtin_amdgcn_mfma_f32_32x32x16_bf16(kf, qf[c], accS[c & 1], 0, 0, 0);
    }

    // in-register softmax: p=exp(s); pack own[G][w] bf16 pairs.
    unsigned own0[2], own1[2], own2[2], own3[2];
    {
      float ss = 0.f;
#pragma unroll
      for (int G = 0; G < 4; ++G) {
        float p0 = __expf(accS[0][4*G+0] + accS[1][4*G+0]);
        float p1 = __expf(accS[0][4*G+1] + accS[1][4*G+1]);
        float p2 = __expf(accS[0][4*G+2] + accS[1][4*G+2]);
        float p3 = __expf(accS[0][4*G+3] + accS[1][4*G+3]);
        ss += (p0 + p1) + (p2 + p3);
        unsigned wa = pkbf(p0, p1), wb = pkbf(p2, p3);
        if (G == 0) { own0[0] = wa; own0[1] = wb; }
        if (G == 1) { own1[0] = wa; own1[1] = wb; }
        if (G == 2) { own2[0] = wa; own2[1] = wb; }
        if (G == 3) { own3[0] = wa; own3[1] = wb; }
      }
      sumP += ss;
    }

    // PV: per ks, assemble pa (A-frag, row=q) via 2-word half-exchange.
#pragma unroll
    for (int ks = 0; ks < 2; ++ks) {
      unsigned xa, xb;
      if (ks == 0) { xa = l5 ? own0[0] : own1[0]; xb = l5 ? own0[1] : own1[1]; }
      else         { xa = l5 ? own2[0] : own3[0]; xb = l5 ? own2[1] : own3[1]; }
      unsigned ra = __shfl_xor((int)xa, 32);
      unsigned rb = __shfl_xor((int)xb, 32);
      uint4 uw;
      if (ks == 0) {
        uw.x = l5 ? ra : own0[0];  uw.y = l5 ? rb : own0[1];
        uw.z = l5 ? own1[0] : ra;  uw.w = l5 ? own1[1] : rb;
      } else {
        uw.x = l5 ? ra : own2[0];  uw.y = l5 ? rb : own2[1];
        uw.z = l5 ? own3[0] : ra;  uw.w = l5 ? own3[1] : rb;
      }
      bf16x8 pa = __builtin_bit_cast(bf16x8, uw);
#pragma unroll
      for (int dt = 0; dt < 4; ++dt) {
        bf16x8 vf = *(const bf16x8*)(smemB + VIMM + offV[ks][dt]);
        accO[dt] = __builtin_amdgcn_mfma_f32_32x32x16_bf16(pa, vf, accO[dt], 0, 0, 0);
      }
    }
  };

  stageTo(0);   // tile 0 -> buf0

#pragma unroll 1
  for (int t = 0; t < 32; t += 2) {
    // even tile: read buf0, prefetch t+1 -> buf1
    __syncthreads();            // drains stage(t) DMA; WAR-protects buf1
    stageTo(8192);              // t+1 <= 31 always (t <= 30)
    computeTile(0, 32768);
    // odd tile: read buf1, prefetch t+2 -> buf0
    __syncthreads();            // drains stage(t+1) DMA; WAR-protects buf0
    if (t + 2 < 32) stageTo(0);
    computeTile(16384, 32768 + 16384);
  }

  // ---- finalize row sums: add the complementary 16-key half per q=c31 ----
  {
    float s = sumP;
    s += __shfl_xor(s, 32);
    lStat[(qg*2 + kh)*32 + c31] = s;   // both halves same value: benign dup
  }

  // ---- pair merge: kh=1 parks unnormalized O, kh=0 combines ----
  float* lO = (float*)smem;   // [4 qg][32 q][128 d] f32 = 64 KB over bufK/V
  __syncthreads();            // all tile reads done; lStat visible
  if (kh == 1) {
#pragma unroll
    for (int dt = 0; dt < 4; ++dt)
#pragma unroll
      for (int g = 0; g < 16; ++g) {
        int R = (g & 3) + 8*(g >> 2) + 4*l5;
        lO[(qg*32 + R)*128 + dt*32 + c31] = accO[dt][g];
      }
  }
  __syncthreads();
  if (kh == 0) {
    int b = bh >> 3, h = bh & 7;
#pragma unroll
    for (int g = 0; g < 16; ++g) {
      int R = (g & 3) + 8*(g >> 2) + 4*l5;
      float linv = 1.f / (lStat[(qg*2)*32 + R] + lStat[(qg*2 + 1)*32 + R]);
#pragma unroll
      for (int dt = 0; dt < 4; ++dt) {
        float v = (accO[dt][g] + lO[(qg*32 + R)*128 + dt*32 + c31]) * linv;
        Sout[((long)(b*2048 + q0 + R))*1024 + h*128 + dt*32 + c31] = f2bf(v);
      }
    }
  }
}

// ---------------------------------------------------------------------------
// Output projection v3 — v2 + XCD-aware role remap (same scheme as qkv:
// the 8 channel-tile blocks sharing one token-panel of S co-locate on one
// XCD; each XCD owns 4 complete panels -> S (8MB) L2-resident per XCD
// instead of streamed 8x).
// ---------------------------------------------------------------------------
__global__ __launch_bounds__(256, 3)
void k_gemm_out(const u16* __restrict__ S, const u16* __restrict__ WoT,
                const float* __restrict__ bo, float* __restrict__ out)
{
  __shared__ u16 lA[4096], lB[4096];
  int tid = threadIdx.x;
  int bx = blockIdx.y & 7;                       // channel-tile role [0,8)
  int by = blockIdx.x * 4 + (blockIdx.y >> 3);   // token-panel role [0,32)
  int m0 = bx * 128, n0 = by * 128;              // m = channel, n = token
  f32x4 acc[4][4] = {};
  gemm_main_128x128(WoT, S, lA, lB, m0, n0, tid, acc);

  int w = tid >> 6, l = tid & 63, quad = l >> 4, lm = l & 15;
  int wm = w >> 1, wn = w & 1;
#pragma unroll
  for (int mi = 0; mi < 4; ++mi) {
    int chb = m0 + wm*64 + mi*16 + quad*4;   // 4 consecutive channels
    float4 bb = *(const float4*)(bo + chb);
#pragma unroll
    for (int ni = 0; ni < 4; ++ni) {
      int tok = n0 + wn*64 + ni*16 + lm;
      float4 v;
      v.x = acc[mi][ni][0] + bb.x;
      v.y = acc[mi][ni][1] + bb.y;
      v.z = acc[mi][ni][2] + bb.z;
      v.w = acc[mi][ni][3] + bb.w;
      *(float4*)(out + (long)tok * 1024 + chb) = v;
    }
  }
}

// ---------------------------------------------------------------------------
// ws layout (u16 elems), 48 MiB: ABUF (q_bf16, reused for summed), KVB,
// WT 4x, Qb/Kb [b][h][n][d], VTb [b][h][d][n]
// ---------------------------------------------------------------------------
extern "C" void kernel_launch(void* const* d_in, const int* in_sizes, int n_in,
                              void* d_out, int out_size, void* d_ws, size_t ws_size,
                              hipStream_t stream)
{
  const float* inq  = (const float*)d_in[0];
  const float* inkv = (const float*)d_in[1];
  const float* Wq = (const float*)d_in[2];
  const float* bq = (const float*)d_in[3];
  const float* Wk = (const float*)d_in[4];
  const float* bk = (const float*)d_in[5];
  const float* Wv = (const float*)d_in[6];
  const float* bv = (const float*)d_in[7];
  const float* Wo = (const float*)d_in[8];
  const float* bo = (const float*)d_in[9];

  u16* ws   = (u16*)d_ws;
  u16* ABUF = ws;
  u16* KVB  = ws + SZ_IN;
  u16* WT   = ws + 2 * SZ_IN;
  u16* Qb   = WT + 4 * SZ_W;
  u16* Kb   = Qb + SZ_IN;
  u16* VTb  = Kb + SZ_IN;

  k_cast    <<<dim3(2048, 3),   256, 0, stream>>>(inq, inkv, Wq, Wk, Wv, Wo, ABUF, KVB, WT);
  k_gemm_qkv<<<dim3(8, 32, 3),  256, 0, stream>>>(ABUF, KVB, WT, bq, bk, bv, Qb, Kb, VTb);
  k_attn    <<<dim3(16, 16),    512, 0, stream>>>(Qb, Kb, VTb, ABUF);
  k_gemm_out<<<dim3(8, 32),     256, 0, stream>>>(ABUF, WT + 3 * SZ_W, bo, (float*)d_out);
}

// Round 11
// 204.791 us; speedup vs baseline: 1.0671x; 1.0191x over previous
//
#include <hip/hip_runtime.h>

typedef unsigned short u16;
typedef __bf16 bf16;
typedef __attribute__((ext_vector_type(8))) __bf16 bf16x8;   // MFMA A/B frag (4 VGPRs)
typedef __attribute__((ext_vector_type(4))) float f32x4;     // 16x16 MFMA C/D frag
typedef __attribute__((ext_vector_type(16))) float f32x16;   // 32x32 MFMA C/D frag

#define AS1(p) ((const __attribute__((address_space(1))) void*)(p))
#define AS3(p) ((__attribute__((address_space(3))) void*)(p))

__device__ __forceinline__ u16 f2bf(float f) {
  unsigned u = __builtin_bit_cast(unsigned, f);
  u += 0x7fffu + ((u >> 16) & 1u);
  return (u16)(u >> 16);
}

// packed bf16 pair (RNE via compiler bf16 casts; may fuse to v_cvt_pk_bf16_f32)
__device__ __forceinline__ unsigned pkbf(float a, float b) {
  unsigned lo = (unsigned)__builtin_bit_cast(unsigned short, (__bf16)a);
  unsigned hi = (unsigned)__builtin_bit_cast(unsigned short, (__bf16)b);
  return lo | (hi << 16);
}

static constexpr int  B_ = 2, N_ = 2048, C_ = 1024, H_ = 8, DH_ = 128;
static constexpr long SZ_IN = (long)B_ * N_ * C_;  // 4,194,304 elems
static constexpr long SZ_W  = (long)C_ * C_;       // 1,048,576 elems

// ---------------------------------------------------------------------------
// Fused cast kernel (unchanged).
// ---------------------------------------------------------------------------
__global__ void k_cast(const float* __restrict__ q, const float* __restrict__ kv,
                       const float* __restrict__ W0, const float* __restrict__ W1,
                       const float* __restrict__ W2, const float* __restrict__ W3,
                       u16* __restrict__ qb, u16* __restrict__ kvb,
                       u16* __restrict__ WT)
{
  __shared__ u16 t[64][65];
  int tid = threadIdx.x;
  if (blockIdx.y < 2) {
    const float* src = blockIdx.y ? kv : q;
    u16* dst = blockIdx.y ? kvb : qb;
    long i = ((long)blockIdx.x * 256 + tid) * 8;
    float4 a = *(const float4*)(src + i);
    float4 b = *(const float4*)(src + i + 4);
    uint4 v;
    v.x = f2bf(a.x) | ((unsigned)f2bf(a.y) << 16);
    v.y = f2bf(a.z) | ((unsigned)f2bf(a.w) << 16);
    v.z = f2bf(b.x) | ((unsigned)f2bf(b.y) << 16);
    v.w = f2bf(b.z) | ((unsigned)f2bf(b.w) << 16);
    *(uint4*)(dst + i) = v;
    return;
  }
  int x = blockIdx.x;
  if (x >= 1024) return;
  int z = x >> 8, tile = x & 255;
  const float* W = (z == 0) ? W0 : (z == 1) ? W1 : (z == 2) ? W2 : W3;
  u16* dst = WT + (long)z * SZ_W;
  int n0 = (tile & 15) * 64, k0 = (tile >> 4) * 64;
#pragma unroll
  for (int r = 0; r < 4; ++r) {
    int slot = r * 256 + tid;
    int row = slot >> 4, c4 = slot & 15;
    float4 a = *(const float4*)(W + (long)(k0 + row) * 1024 + n0 + c4 * 4);
    t[c4*4+0][row] = f2bf(a.x);
    t[c4*4+1][row] = f2bf(a.y);
    t[c4*4+2][row] = f2bf(a.z);
    t[c4*4+3][row] = f2bf(a.w);
  }
  __syncthreads();
#pragma unroll
  for (int r = 0; r < 4; ++r) {
    int slot = r * 256 + tid;
    int row = slot >> 4, c4 = slot & 15;
    uint2 v;
    v.x = t[row][c4*4+0] | ((unsigned)t[row][c4*4+1] << 16);
    v.y = t[row][c4*4+2] | ((unsigned)t[row][c4*4+3] << 16);
    *(uint2*)(dst + (long)(n0 + row) * 1024 + k0 + c4 * 4) = v;
  }
}

// ---------------------------------------------------------------------------
// m97-style GEMM mainloop (unchanged; used by k_gemm_qkv).
// ---------------------------------------------------------------------------
__device__ __forceinline__ void gemm_main_128x128(
    const u16* __restrict__ A, const u16* __restrict__ BT,
    u16* lA, u16* lB, int m0, int n0, int tid, f32x4 acc[4][4])
{
  int w = tid >> 6, l = tid & 63, quad = l >> 4, lm = l & 15;
  int wm = w >> 1, wn = w & 1;
  int srow = tid >> 2, schunk = tid & 3;
  int sxw = (srow >> 1) & 3;
  int sxr = (lm >> 1) & 3;
  const u16* Ag = A + (long)(m0 + srow) * 1024 + (schunk ^ sxw) * 8;
  const u16* Bg = BT + (long)(n0 + srow) * 1024 + (schunk ^ sxw) * 8;
  u16* lAw = lA + w * 512;
  u16* lBw = lB + w * 512;
  for (int kb = 0; kb < 32; ++kb) {
    const u16* Agk = Ag + kb * 32;
    const u16* Bgk = Bg + kb * 32;
    __builtin_amdgcn_global_load_lds(AS1(Agk),           AS3(lAw),        16, 0, 0);
    __builtin_amdgcn_global_load_lds(AS1(Agk + 64*1024), AS3(lAw + 2048), 16, 0, 0);
    __builtin_amdgcn_global_load_lds(AS1(Bgk),           AS3(lBw),        16, 0, 0);
    __builtin_amdgcn_global_load_lds(AS1(Bgk + 64*1024), AS3(lBw + 2048), 16, 0, 0);
    __syncthreads();
    bf16x8 af[4], bfr[4];
#pragma unroll
    for (int mi = 0; mi < 4; ++mi)
      af[mi] = *(const bf16x8*)(lA + (wm*64 + mi*16 + lm)*32 + ((quad ^ sxr))*8);
#pragma unroll
    for (int ni = 0; ni < 4; ++ni)
      bfr[ni] = *(const bf16x8*)(lB + (wn*64 + ni*16 + lm)*32 + ((quad ^ sxr))*8);
#pragma unroll
    for (int mi = 0; mi < 4; ++mi)
#pragma unroll
      for (int ni = 0; ni < 4; ++ni)
        acc[mi][ni] = __builtin_amdgcn_mfma_f32_16x16x32_bf16(af[mi], bfr[ni], acc[mi][ni], 0, 0, 0);
    __syncthreads();
  }
}

// ---------------------------------------------------------------------------
// QKV projection v3 (unchanged from round 10).
// ---------------------------------------------------------------------------
__global__ __launch_bounds__(256, 3)
void k_gemm_qkv(const u16* __restrict__ qb, const u16* __restrict__ kvb,
                const u16* __restrict__ wt,
                const float* __restrict__ bq, const float* __restrict__ bk,
                const float* __restrict__ bv,
                u16* __restrict__ Qb, u16* __restrict__ Kb, u16* __restrict__ VTb)
{
  __shared__ u16 lA[4096], lB[4096];
  int tid = threadIdx.x;
  int z = blockIdx.z;
  f32x4 acc[4][4] = {};
  int w = tid >> 6, l = tid & 63, quad = l >> 4, lm = l & 15;
  int wm = w >> 1, wn = w & 1;

  int bx = blockIdx.y & 7;                       // channel-tile role [0,8)
  int by = blockIdx.x * 4 + (blockIdx.y >> 3);   // token-panel role [0,32)

  if (z == 2) {
    int m0 = by * 128, n0 = bx * 128;
    gemm_main_128x128(kvb, wt + 2 * SZ_W, lA, lB, m0, n0, tid, acc);
#pragma unroll
    for (int ni = 0; ni < 4; ++ni) {
      int n = n0 + wn*64 + ni*16 + lm;       // channel
      float bb = bv[n];
      int h = n >> 7, dd = n & 127;
#pragma unroll
      for (int mi = 0; mi < 4; ++mi) {
        int mbase = m0 + wm*64 + mi*16 + quad*4;  // token (4 consecutive)
        int bidx = mbase >> 11, nn = mbase & 2047;
        u16 o0 = f2bf(acc[mi][ni][0] + bb), o1 = f2bf(acc[mi][ni][1] + bb);
        u16 o2 = f2bf(acc[mi][ni][2] + bb), o3 = f2bf(acc[mi][ni][3] + bb);
        uint2 v; v.x = o0 | ((unsigned)o1 << 16); v.y = o2 | ((unsigned)o3 << 16);
        *(uint2*)(VTb + ((long)(bidx*8 + h)*128 + dd)*2048 + nn) = v;
      }
    }
  } else {
    const u16* X = (z == 0) ? qb : kvb;
    const float* bias = (z == 0) ? bq : bk;
    u16* dst = (z == 0) ? Qb : Kb;
    float scale = (z == 0) ? 0.08838834764831845f : 1.0f;  // fold 1/sqrt(128)
    int m0 = bx * 128, n0 = by * 128;
    gemm_main_128x128(wt + (long)z * SZ_W, X, lA, lB, m0, n0, tid, acc);
#pragma unroll
    for (int mi = 0; mi < 4; ++mi) {
      int chb = m0 + wm*64 + mi*16 + quad*4;   // channel base (4 consecutive)
      int h = chb >> 7, d = chb & 127;
      float4 bb = *(const float4*)(bias + chb);
#pragma unroll
      for (int ni = 0; ni < 4; ++ni) {
        int tok = n0 + wn*64 + ni*16 + lm;
        int bidx = tok >> 11, nn = tok & 2047;
        u16 o0 = f2bf((acc[mi][ni][0] + bb.x) * scale);
        u16 o1 = f2bf((acc[mi][ni][1] + bb.y) * scale);
        u16 o2 = f2bf((acc[mi][ni][2] + bb.z) * scale);
        u16 o3 = f2bf((acc[mi][ni][3] + bb.w) * scale);
        uint2 v; v.x = o0 | ((unsigned)o1 << 16); v.y = o2 | ((unsigned)o3 << 16);
        *(uint2*)(dst + ((long)(bidx*8 + h)*2048 + nn)*128 + d) = v;
      }
    }
  }
}

// ---------------------------------------------------------------------------
// Flash attention v17 (unchanged, 50.0us round-10-proven).
// ---------------------------------------------------------------------------
__global__ __launch_bounds__(512, 2)
void k_attn(const u16* __restrict__ Qb, const u16* __restrict__ Kb,
            const u16* __restrict__ VTb, u16* __restrict__ Sout)
{
  __shared__ u16 smem[33280];   // 65 KB
  float* lStat = (float*)(smem + 32768);  // [4 qg][2 kh][32 q]

  int tid = threadIdx.x;
  int w = tid >> 6, l = tid & 63;
  int l5 = l >> 5, c31 = l & 31;
  int qg = w >> 1, kh = w & 1;
  int bh = blockIdx.x;             // XCD = bh % 8 -> 2 bh per XCD L2
  int q0 = blockIdx.y * 128 + qg * 32;
  const u16* Qg = Qb + ((long)bh * 2048 + q0) * 128;
  const u16* Kg = Kb + (long)bh * 2048 * 128;
  const u16* Vg = VTb + (long)bh * 128 * 2048;

  // register-resident Q: qf[c] = Q[q=c31][d = c*16 + l5*8 + j]
  bf16x8 qf[8];
#pragma unroll
  for (int c = 0; c < 8; ++c)
    qf[c] = *(const bf16x8*)(Qg + (long)c31 * 128 + c*16 + l5*8);

  // ---- loop-invariant per-lane LDS byte offsets (fit ds_read imm+off) ----
  int offK[8];
#pragma unroll
  for (int c = 0; c < 8; ++c) {
    int r = kh*32 + c31;
    offK[c] = (r*16 + ((2*c + l5) ^ (l & 15))) * 16;       // < 16384
  }
  int offV[2][4];
#pragma unroll
  for (int ks = 0; ks < 2; ++ks)
#pragma unroll
    for (int dt = 0; dt < 4; ++dt) {
      int d = dt*32 + c31;
      int cc = kh*4 + ks*2 + l5;
      offV[ks][dt] = (d*8 + (cc ^ (d & 7))) * 16;          // < 16384
    }

  // ---- persistent staging src pointers (advance one tile per stage) ----
  const u16* sK[2];
  const u16* sV[2];
#pragma unroll
  for (int j = 0; j < 2; ++j) {
    int s = j*512 + tid;             // 0..1023
    int r = s >> 4, sl = s & 15;     // key row 0..63, stored slot
    sK[j] = Kg + (long)r*128 + ((sl ^ (r & 15)) * 8);
    int d = s >> 3, sv = s & 7;      // d row 0..127, stored slot
    sV[j] = Vg + (long)d*2048 + ((sv ^ (d & 7)) * 8);
  }

  f32x16 accO[4] = {};   // [dtile]; row=q via R(g,l5), col=d=dtile*32+c31
  float sumP = 0.f;      // per-lane: q=c31, own 16 keys/tile, all tiles

  const char* smemB = (const char*)smem;

  // stage next tile into buffer at u16-elem offset bufe (0 or 8192)
  auto stageTo = [&](int bufe) {
#pragma unroll
    for (int j = 0; j < 2; ++j) {
      __builtin_amdgcn_global_load_lds(AS1(sK[j]),
          AS3(smem + bufe + (j*512 + w*64)*8), 16, 0, 0);
      sK[j] += 64*128;   // one 64-key tile forward
    }
#pragma unroll
    for (int j = 0; j < 2; ++j) {
      __builtin_amdgcn_global_load_lds(AS1(sV[j]),
          AS3(smem + 16384 + bufe + (j*512 + w*64)*8), 16, 0, 0);
      sV[j] += 64;       // one 64-key tile forward (row-major stride 2048)
    }
  };

  // compute one 64-key tile from buffers at byte imm KIMM/VIMM (literals)
  auto computeTile = [&](int KIMM, int VIMM) {
    // QK^T SWAPPED: accS = K_half x Q -> S[key][q]; 8 MFMAs, 2 acc chains.
    f32x16 accS[2] = {};
#pragma unroll
    for (int c = 0; c < 8; ++c) {
      bf16x8 kf = *(const bf16x8*)(smemB + KIMM + offK[c]);
      accS[c & 1] = __builtin_amdgcn_mfma_f32_32x32x16_bf16(kf, qf[c], accS[c & 1], 0, 0, 0);
    }

    // in-register softmax: p=exp(s); pack own[G][w] bf16 pairs.
    unsigned own0[2], own1[2], own2[2], own3[2];
    {
      float ss = 0.f;
#pragma unroll
      for (int G = 0; G < 4; ++G) {
        float p0 = __expf(accS[0][4*G+0] + accS[1][4*G+0]);
        float p1 = __expf(accS[0][4*G+1] + accS[1][4*G+1]);
        float p2 = __expf(accS[0][4*G+2] + accS[1][4*G+2]);
        float p3 = __expf(accS[0][4*G+3] + accS[1][4*G+3]);
        ss += (p0 + p1) + (p2 + p3);
        unsigned wa = pkbf(p0, p1), wb = pkbf(p2, p3);
        if (G == 0) { own0[0] = wa; own0[1] = wb; }
        if (G == 1) { own1[0] = wa; own1[1] = wb; }
        if (G == 2) { own2[0] = wa; own2[1] = wb; }
        if (G == 3) { own3[0] = wa; own3[1] = wb; }
      }
      sumP += ss;
    }

    // PV: per ks, assemble pa (A-frag, row=q) via 2-word half-exchange.
#pragma unroll
    for (int ks = 0; ks < 2; ++ks) {
      unsigned xa, xb;
      if (ks == 0) { xa = l5 ? own0[0] : own1[0]; xb = l5 ? own0[1] : own1[1]; }
      else         { xa = l5 ? own2[0] : own3[0]; xb = l5 ? own2[1] : own3[1]; }
      unsigned ra = __shfl_xor((int)xa, 32);
      unsigned rb = __shfl_xor((int)xb, 32);
      uint4 uw;
      if (ks == 0) {
        uw.x = l5 ? ra : own0[0];  uw.y = l5 ? rb : own0[1];
        uw.z = l5 ? own1[0] : ra;  uw.w = l5 ? own1[1] : rb;
      } else {
        uw.x = l5 ? ra : own2[0];  uw.y = l5 ? rb : own2[1];
        uw.z = l5 ? own3[0] : ra;  uw.w = l5 ? own3[1] : rb;
      }
      bf16x8 pa = __builtin_bit_cast(bf16x8, uw);
#pragma unroll
      for (int dt = 0; dt < 4; ++dt) {
        bf16x8 vf = *(const bf16x8*)(smemB + VIMM + offV[ks][dt]);
        accO[dt] = __builtin_amdgcn_mfma_f32_32x32x16_bf16(pa, vf, accO[dt], 0, 0, 0);
      }
    }
  };

  stageTo(0);   // tile 0 -> buf0

#pragma unroll 1
  for (int t = 0; t < 32; t += 2) {
    // even tile: read buf0, prefetch t+1 -> buf1
    __syncthreads();            // drains stage(t) DMA; WAR-protects buf1
    stageTo(8192);              // t+1 <= 31 always (t <= 30)
    computeTile(0, 32768);
    // odd tile: read buf1, prefetch t+2 -> buf0
    __syncthreads();            // drains stage(t+1) DMA; WAR-protects buf0
    if (t + 2 < 32) stageTo(0);
    computeTile(16384, 32768 + 16384);
  }

  // ---- finalize row sums: add the complementary 16-key half per q=c31 ----
  {
    float s = sumP;
    s += __shfl_xor(s, 32);
    lStat[(qg*2 + kh)*32 + c31] = s;   // both halves same value: benign dup
  }

  // ---- pair merge: kh=1 parks unnormalized O, kh=0 combines ----
  float* lO = (float*)smem;   // [4 qg][32 q][128 d] f32 = 64 KB over bufK/V
  __syncthreads();            // all tile reads done; lStat visible
  if (kh == 1) {
#pragma unroll
    for (int dt = 0; dt < 4; ++dt)
#pragma unroll
      for (int g = 0; g < 16; ++g) {
        int R = (g & 3) + 8*(g >> 2) + 4*l5;
        lO[(qg*32 + R)*128 + dt*32 + c31] = accO[dt][g];
      }
  }
  __syncthreads();
  if (kh == 0) {
    int b = bh >> 3, h = bh & 7;
#pragma unroll
    for (int g = 0; g < 16; ++g) {
      int R = (g & 3) + 8*(g >> 2) + 4*l5;
      float linv = 1.f / (lStat[(qg*2)*32 + R] + lStat[(qg*2 + 1)*32 + R]);
#pragma unroll
      for (int dt = 0; dt < 4; ++dt) {
        float v = (accO[dt][g] + lO[(qg*32 + R)*128 + dt*32 + c31]) * linv;
        Sout[((long)(b*2048 + q0 + R))*1024 + h*128 + dt*32 + c31] = f2bf(v);
      }
    }
  }
}

// ---------------------------------------------------------------------------
// Output projection v4 — 128x64 tiles for 2-block/CU co-residency.
//
// Accounting after r10: non-attn ~158us with every kernel <50us (absent from
// top-5). Closure: cast ~12, qkv ~45-50 (520-570 TF, 3 blocks/CU), gaps
// ~10-15 => gemm_out ~30-36us (8.6 GFLOP -> ~240-290 TF). Its handicap:
// grid (8,32) = 256 blocks = EXACTLY 1 block/CU -> the m97 2-barrier loop's
// whole-CU barrier drain has no co-resident block to overlap with (m102:
// 1-block/CU GEMM ~320 TF vs 900+ at 3/CU; m114: the stall is recovered
// only via co-residency). qkv escapes this with 768 blocks.
//
// v4: 128(ch) x 64(tok) tiles -> grid (8,64) = 512 blocks = 2 blocks/CU.
// Main loop = gemm_main with B-side halved: B-tile 64x32 (1 DMA/thread),
// bfr 2 frags, acc 4x2, per-wave output 64x32. All swizzle/read formulas
// carried index-for-index (sxr identity holds: row = 16k+lm). Per-CU DMA
// volume unchanged (B-tile halves, blocks double; A re-reads double but
// A = 2MB weights, L2-resident). LDS 12KB -> 2 blocks easily co-resident.
// ---------------------------------------------------------------------------
__global__ __launch_bounds__(256, 3)
void k_gemm_out(const u16* __restrict__ S, const u16* __restrict__ WoT,
                const float* __restrict__ bo, float* __restrict__ out)
{
  __shared__ u16 lA[4096], lB[2048];
  int tid = threadIdx.x;
  int m0 = blockIdx.x * 128;       // channel tile [0,8)
  int n0 = blockIdx.y * 64;        // token panel [0,64)

  int w = tid >> 6, l = tid & 63, quad = l >> 4, lm = l & 15;
  int wm = w >> 1, wn = w & 1;
  int srow = tid >> 2, schunk = tid & 3;
  int sxw = (srow >> 1) & 3;
  int sxr = (lm >> 1) & 3;

  f32x4 acc[4][2] = {};

  const u16* Ag = WoT + (long)(m0 + srow) * 1024 + (schunk ^ sxw) * 8;
  const u16* Bg = S   + (long)(n0 + srow) * 1024 + (schunk ^ sxw) * 8;  // srow<64
  u16* lAw = lA + w * 512;
  u16* lBw = lB + w * 512;

  for (int kb = 0; kb < 32; ++kb) {
    const u16* Agk = Ag + kb * 32;
    const u16* Bgk = Bg + kb * 32;
    __builtin_amdgcn_global_load_lds(AS1(Agk),           AS3(lAw),        16, 0, 0);
    __builtin_amdgcn_global_load_lds(AS1(Agk + 64*1024), AS3(lAw + 2048), 16, 0, 0);
    __builtin_amdgcn_global_load_lds(AS1(Bgk),           AS3(lBw),        16, 0, 0);
    __syncthreads();
    bf16x8 af[4], bfr[2];
#pragma unroll
    for (int mi = 0; mi < 4; ++mi)
      af[mi] = *(const bf16x8*)(lA + (wm*64 + mi*16 + lm)*32 + ((quad ^ sxr))*8);
#pragma unroll
    for (int ni = 0; ni < 2; ++ni)
      bfr[ni] = *(const bf16x8*)(lB + (wn*32 + ni*16 + lm)*32 + ((quad ^ sxr))*8);
#pragma unroll
    for (int mi = 0; mi < 4; ++mi)
#pragma unroll
      for (int ni = 0; ni < 2; ++ni)
        acc[mi][ni] = __builtin_amdgcn_mfma_f32_16x16x32_bf16(af[mi], bfr[ni], acc[mi][ni], 0, 0, 0);
    __syncthreads();
  }

#pragma unroll
  for (int mi = 0; mi < 4; ++mi) {
    int chb = m0 + wm*64 + mi*16 + quad*4;   // 4 consecutive channels
    float4 bb = *(const float4*)(bo + chb);
#pragma unroll
    for (int ni = 0; ni < 2; ++ni) {
      int tok = n0 + wn*32 + ni*16 + lm;
      float4 v;
      v.x = acc[mi][ni][0] + bb.x;
      v.y = acc[mi][ni][1] + bb.y;
      v.z = acc[mi][ni][2] + bb.z;
      v.w = acc[mi][ni][3] + bb.w;
      *(float4*)(out + (long)tok * 1024 + chb) = v;
    }
  }
}

// ---------------------------------------------------------------------------
// ws layout (u16 elems), 48 MiB: ABUF (q_bf16, reused for summed), KVB,
// WT 4x, Qb/Kb [b][h][n][d], VTb [b][h][d][n]
// ---------------------------------------------------------------------------
extern "C" void kernel_launch(void* const* d_in, const int* in_sizes, int n_in,
                              void* d_out, int out_size, void* d_ws, size_t ws_size,
                              hipStream_t stream)
{
  const float* inq  = (const float*)d_in[0];
  const float* inkv = (const float*)d_in[1];
  const float* Wq = (const float*)d_in[2];
  const float* bq = (const float*)d_in[3];
  const float* Wk = (const float*)d_in[4];
  const float* bk = (const float*)d_in[5];
  const float* Wv = (const float*)d_in[6];
  const float* bv = (const float*)d_in[7];
  const float* Wo = (const float*)d_in[8];
  const float* bo = (const float*)d_in[9];

  u16* ws   = (u16*)d_ws;
  u16* ABUF = ws;
  u16* KVB  = ws + SZ_IN;
  u16* WT   = ws + 2 * SZ_IN;
  u16* Qb   = WT + 4 * SZ_W;
  u16* Kb   = Qb + SZ_IN;
  u16* VTb  = Kb + SZ_IN;

  k_cast    <<<dim3(2048, 3),   256, 0, stream>>>(inq, inkv, Wq, Wk, Wv, Wo, ABUF, KVB, WT);
  k_gemm_qkv<<<dim3(8, 32, 3),  256, 0, stream>>>(ABUF, KVB, WT, bq, bk, bv, Qb, Kb, VTb);
  k_attn    <<<dim3(16, 16),    512, 0, stream>>>(Qb, Kb, VTb, ABUF);
  k_gemm_out<<<dim3(8, 64),     256, 0, stream>>>(ABUF, WT + 3 * SZ_W, bo, (float*)d_out);
}